// Round 2
// baseline (1640.845 us; speedup 1.0000x reference)
//
#include <hip/hip_runtime.h>

// ---------------- types / helpers ----------------
typedef unsigned short u16;
typedef short short8 __attribute__((ext_vector_type(8)));
typedef float f32x4 __attribute__((ext_vector_type(4)));

__device__ __forceinline__ float b2f(u16 u) {
    unsigned x = ((unsigned)u) << 16;
    return __builtin_bit_cast(float, x);
}
__device__ __forceinline__ u16 f2b(float f) {
    unsigned u = __builtin_bit_cast(unsigned, f);
    u += 0x7FFFu + ((u >> 16) & 1u);   // RNE
    return (u16)(u >> 16);
}
__device__ __forceinline__ float sigm(float x) { return 1.f / (1.f + __expf(-x)); }
__device__ __forceinline__ float tanh_(float x) { return 1.f - 2.f / (__expf(2.f * x) + 1.f); }

// ---------------- problem constants ----------------
#define T_STEPS 128
#define BATCH   32
#define KHR     320      // 64 (read) + 256 (h)
#define PADK    328      // hr_lds row pad (bf16 elems)
#define MEMPAD  68       // mem row stride in floats
#define WKPAD   264      // wkeyT row pad (bf16 elems)

// ---------------- workspace layout (bytes) ----------------
#define WS_BAR      0
#define WS_LOSS     64
#define WS_FLAG     96
#define WS_HRG      128                       // u16 [2][32][320] = 40960
#define WS_ZSET     41088                     // memset range end
// normalized fp32 inputs
#define WS_XSF      41216                     // 524288 f32
#define WS_MEM0F    2138368                   // 524288 f32
#define WS_WLF      4235520                   // 655360 f32
#define WS_BLF      6856960                   // 1024 f32
#define WS_WPREF    6861056                   // 32768 f32
#define WS_BPREF    6992128                   // 128 f32
#define WS_WKEYF    6992640                   // 16384 f32
#define WS_WBETAF   7058176                   // 256 f32
#define WS_WTEACHF  7059200                   // 16384 f32
#define WS_WROF     7124736                   // 32768 f32
// derived
#define WS_XW       7255808                   // f32 [4096][1024] = 16777216
#define WS_WREFF    24033024                  // f32 [64][1024]   = 262144
#define WS_WKT      24295168                  // f32 [256][64]    = 65536
#define WS_WROEFF   24360704                  // f32 [64][128]    = 32768
#define WS_HS       24393472                  // f32 [4096][256]  = 4194304
#define WS_RS       28587776                  // f32 [4096][64]   = 1048576
// total ~29.6 MB

// ---------------- LDS layout (bytes) ----------------
#define HR_OFF   0         // u16 [32][328]            20992
#define WF_OFF   20992     // u16 [10][4][32][8]       20480
#define WK_OFF   41472     // u16 [64][264]            33792
#define MEM_OFF  75264     // f32 [256][68]            69632
#define Z_OFF    144896    // f32 [32][36]             4608
#define C_OFF    149504    // f32 [32][8]              1024
#define HB_OFF   150528    // f32 [256]                1024
#define KV_OFF   151552    // f32 [64]                 256
#define WW_OFF   151808    // f32 [256]                1024
#define KP_OFF   152832    // f32 [4][64]              1024
#define RP_OFF   153856    // f32 [4][64]              1024
#define BR_OFF   154880    // f32 [16]
#define WR_OFF   154944    // f32 [16]
#define SC_OFF   155008    // f32 scalars
#define WB_OFF   155072    // f32 [256]                1024
#define LDS_TOTAL 156096

// ---------------- grid barrier (32 resident wgs) ----------------
__device__ __forceinline__ void gridbar(unsigned* bar, unsigned phase) {
    __syncthreads();
    if (threadIdx.x == 0) {
        __builtin_amdgcn_fence(__ATOMIC_RELEASE, "agent");
        __hip_atomic_fetch_add(bar, 1u, __ATOMIC_RELAXED, __HIP_MEMORY_SCOPE_AGENT);
        const unsigned tgt = phase * 32u;
        long guard = 0;
        while (__hip_atomic_load(bar, __ATOMIC_RELAXED, __HIP_MEMORY_SCOPE_AGENT) < tgt) {
            __builtin_amdgcn_s_sleep(2);
            if (++guard > 10000000L) break;   // bail instead of hanging the bench
        }
        __builtin_amdgcn_fence(__ATOMIC_ACQUIRE, "agent");
    }
    __syncthreads();
}

// ---------------- dtype probe: f32 vs bf16 ----------------
// f32 N(0,1) buffer as u16: even halves uniform-random (~15% plausible exp),
// odd halves plausible -> ~58% total. bf16 buffer: ~100% plausible.
__global__ void dnc_probe(const u16* __restrict__ xs_u16, char* __restrict__ ws) {
    __shared__ int cnt;
    if (threadIdx.x == 0) cnt = 0;
    __syncthreads();
    int c = 0;
    for (int i = threadIdx.x; i < 1024; i += 256) {
        int e = (xs_u16[i] >> 7) & 0xFF;
        if (e >= 96 && e <= 135) c++;
    }
    atomicAdd(&cnt, c);
    __syncthreads();
    if (threadIdx.x == 0) *(int*)(ws + WS_FLAG) = (cnt > 820) ? 1 : 0;   // 1 = bf16
}

// ---------------- normalize all inputs to fp32 in ws ----------------
__global__ void dnc_normalize(const void* s0, const void* s1, const void* s2, const void* s3,
                              const void* s4, const void* s5, const void* s6, const void* s7,
                              const void* s8, const void* s9, char* __restrict__ ws) {
    const void* srcs[10] = {s0, s1, s2, s3, s4, s5, s6, s7, s8, s9};
    const int sizes[10] = {524288, 524288, 655360, 1024, 32768, 128, 16384, 256, 16384, 32768};
    const int bases[10] = {WS_XSF, WS_MEM0F, WS_WLF, WS_BLF, WS_WPREF, WS_BPREF,
                           WS_WKEYF, WS_WBETAF, WS_WTEACHF, WS_WROF};
    const int bf = *(const int*)(ws + WS_FLAG);
    const int gt = blockIdx.x * 256 + threadIdx.x, gs = gridDim.x * 256;
    for (int s = 0; s < 10; ++s) {
        float* dst = (float*)(ws + bases[s]);
        const int n = sizes[s];
        if (bf) {
            const u16* p = (const u16*)srcs[s];
            for (int i = gt; i < n; i += gs) dst[i] = b2f(p[i]);
        } else {
            const float* p = (const float*)srcs[s];
            for (int i = gt; i < n; i += gs) dst[i] = p[i];
        }
    }
}

// ---------------- prologue: xW precompute + weight folds (fp32) ----------------
__global__ void dnc_prologue(char* __restrict__ ws) {
    const float* XSF     = (const float*)(ws + WS_XSF);
    const float* WLF     = (const float*)(ws + WS_WLF);
    const float* BLF     = (const float*)(ws + WS_BLF);
    const float* WKEYF   = (const float*)(ws + WS_WKEYF);
    const float* WTEACHF = (const float*)(ws + WS_WTEACHF);
    const float* WROF    = (const float*)(ws + WS_WROF);
    float* xW  = (float*)(ws + WS_XW);
    float* WrE = (float*)(ws + WS_WREFF);
    float* Wkt = (float*)(ws + WS_WKT);
    float* Wre = (float*)(ws + WS_WROEFF);
    const int wg = blockIdx.x, tid = threadIdx.x;
    if (wg < 1024) {
        // xW[r][c] = b_lstm[c] + sum_k X[r][k]*Wl[k][c]   (rows 0..127 of Wl)
        const int r  = wg * 4 + (tid >> 6);
        const int c0 = (tid & 63) * 16;
        float acc[16];
#pragma unroll
        for (int e = 0; e < 16; ++e) acc[e] = BLF[c0 + e];
        for (int k = 0; k < 128; ++k) {
            float xv = XSF[r * 128 + k];
            const float4* wr = (const float4*)(WLF + (size_t)k * 1024 + c0);
            float4 w0 = wr[0], w1 = wr[1], w2 = wr[2], w3 = wr[3];
            acc[0]  += xv * w0.x; acc[1]  += xv * w0.y; acc[2]  += xv * w0.z; acc[3]  += xv * w0.w;
            acc[4]  += xv * w1.x; acc[5]  += xv * w1.y; acc[6]  += xv * w1.z; acc[7]  += xv * w1.w;
            acc[8]  += xv * w2.x; acc[9]  += xv * w2.y; acc[10] += xv * w2.z; acc[11] += xv * w2.w;
            acc[12] += xv * w3.x; acc[13] += xv * w3.y; acc[14] += xv * w3.z; acc[15] += xv * w3.w;
        }
#pragma unroll
        for (int e = 0; e < 16; ++e) xW[(size_t)r * 1024 + c0 + e] = acc[e];
    } else if (wg < 1088) {
        // W_r_eff[m][c] = sum_{rr<4} W_lstm[128+4m+rr][c]  (rv index = m*4+r)
        const int m = wg - 1024;
        const int c = tid * 4;
#pragma unroll
        for (int e = 0; e < 4; ++e) {
            float s = 0.f;
#pragma unroll
            for (int rr = 0; rr < 4; ++rr) s += WLF[(size_t)(128 + 4 * m + rr) * 1024 + c + e];
            WrE[m * 1024 + c + e] = s;
        }
    } else if (wg < 1104) {
        // Wkt = Wkey - Wteach  [256][64]
        const int i = (wg - 1088) * 1024 + tid * 4;
#pragma unroll
        for (int e = 0; e < 4; ++e) Wkt[i + e] = WKEYF[i + e] - WTEACHF[i + e];
    } else if (wg < 1112) {
        // W_ro_eff[m][c] = sum_{rr<4} W_ro[4m+rr][c]
        const int i = (wg - 1104) * 1024 + tid * 4;
#pragma unroll
        for (int e = 0; e < 4; ++e) {
            int m = (i + e) >> 7, c = (i + e) & 127;
            float s = 0.f;
#pragma unroll
            for (int rr = 0; rr < 4; ++rr) s += WROF[(4 * m + rr) * 128 + c];
            Wre[i + e] = s;
        }
    }
}

// ---------------- main persistent kernel: 32 wgs, 2 grid barriers / step ----------------
__global__ __launch_bounds__(256, 1) void dnc_main(char* __restrict__ ws) {
    extern __shared__ char smem[];
    u16*   hr_lds = (u16*)(smem + HR_OFF);
    u16*   wfrag  = (u16*)(smem + WF_OFF);
    u16*   wkeyT  = (u16*)(smem + WK_OFF);
    float* memA   = (float*)(smem + MEM_OFF);
    float* z_lds  = (float*)(smem + Z_OFF);
    float* c_lds  = (float*)(smem + C_OFF);
    float* hb     = (float*)(smem + HB_OFF);
    float* kv     = (float*)(smem + KV_OFF);
    float* wwts   = (float*)(smem + WW_OFF);
    float* kpart  = (float*)(smem + KP_OFF);
    float* rp     = (float*)(smem + RP_OFF);
    float* bred   = (float*)(smem + BR_OFF);
    float* wred   = (float*)(smem + WR_OFF);
    float* sc     = (float*)(smem + SC_OFF);
    float* wbF    = (float*)(smem + WB_OFF);

    const int tid  = threadIdx.x;
    const int wg   = blockIdx.x;     // col-slice id AND batch id (0..31)
    const int lane = tid & 63;
    const int wid  = tid >> 6;       // wave 0..3

    unsigned* bar = (unsigned*)(ws + WS_BAR);
    u16* hrg      = (u16*)(ws + WS_HRG);               // [2][32][320] bf16
    const float* xWF     = (const float*)(ws + WS_XW);
    const float* WrEffF  = (const float*)(ws + WS_WREFF);
    const float* WLF     = (const float*)(ws + WS_WLF);
    const float* WKEYF   = (const float*)(ws + WS_WKEYF);
    const float* WBETAF  = (const float*)(ws + WS_WBETAF);
    const float* MEM0F   = (const float*)(ws + WS_MEM0F);
    float* HsF = (float*)(ws + WS_HS);
    float* RsF = (float*)(ws + WS_RS);

    // ---- one-time LDS init ----
    // wfrag[kt][q][c][j]: B-frag for MFMA; element k = kt*32+q*8+j, local col c = gate*8+u
    for (int idx = tid; idx < 10240; idx += 256) {
        int k = idx >> 5, c = idx & 31;
        int kt = k >> 5, q = (k >> 3) & 3, j = k & 7;
        int gcol = (c >> 3) * 256 + wg * 8 + (c & 7);
        float v = (k < 64) ? WrEffF[k * 1024 + gcol]
                           : WLF[(size_t)(384 + (k - 64)) * 1024 + gcol];
        wfrag[((kt * 4 + q) * 32 + c) * 8 + j] = f2b(v);
    }
    for (int i = tid; i < 256 * 64; i += 256) {   // wkeyT[m][k] = Wkey[k][m] (bf16)
        int k = i >> 6, m = i & 63;
        wkeyT[m * WKPAD + k] = f2b(WKEYF[i]);
    }
    wbF[tid]   = WBETAF[tid];
    c_lds[tid] = 0.f;
    for (int i = tid; i < 256 * 64; i += 256) {   // mem state fp32
        int n = i >> 6, m = i & 63;
        memA[n * MEMPAD + m] = MEM0F[wg * 16384 + i];
    }
    __syncthreads();

    const int bt = wid & 1, ct = wid >> 1;   // MFMA tile assignment
    const int fm = lane & 15, fq = lane >> 4;
    unsigned bar_phase = 0;

    for (int t = 0; t < T_STEPS; ++t) {
        const int cur = t & 1, nxt = cur ^ 1;

        // ---- Z: stage hr (all 32 batches) from global into padded LDS ----
        {
            const int b  = tid >> 3;
            const int k0 = (tid & 7) * 40;
            const u16* src = hrg + (cur * BATCH + b) * KHR + k0;
            u16* dst = hr_lds + b * PADK + k0;
#pragma unroll
            for (int i = 0; i < 5; ++i)
                *(uint4*)(dst + i * 8) = *(const uint4*)(src + i * 8);
        }
        // prefetch xW gate contributions (fp32)
        const int pb = tid >> 3, pu = tid & 7;
        const size_t xwbase = (size_t)(t * BATCH + pb) * 1024 + wg * 8 + pu;
        float xg0 = xWF[xwbase + 0];
        float xg1 = xWF[xwbase + 256];
        float xg2 = xWF[xwbase + 512];
        float xg3 = xWF[xwbase + 768];
        __syncthreads();

        // ---- MFMA: z[32b x 32cols] = hr(32x320) @ W'(320x32) ----
        f32x4 acc = {0.f, 0.f, 0.f, 0.f};
#pragma unroll
        for (int kt = 0; kt < 10; ++kt) {
            short8 a = *(const short8*)(hr_lds + (bt * 16 + fm) * PADK + kt * 32 + fq * 8);
            short8 b = *(const short8*)(wfrag + ((kt * 4 + fq) * 32 + ct * 16 + fm) * 8);
            acc = __builtin_amdgcn_mfma_f32_16x16x32_bf16(a, b, acc, 0, 0, 0);
        }
#pragma unroll
        for (int r = 0; r < 4; ++r) {
            int bb = bt * 16 + fq * 4 + r;        // C/D: row = quad*4+reg
            int cc = ct * 16 + fm;                //       col = lane&15
            z_lds[bb * 36 + cc] = acc[r];
        }
        __syncthreads();

        // ---- LSTM pointwise for hidden units [8*wg, 8*wg+8), all batches ----
        {
            float iv = z_lds[pb * 36 + pu]      + xg0;
            float fv = z_lds[pb * 36 + 8 + pu]  + xg1;
            float gv = z_lds[pb * 36 + 16 + pu] + xg2;
            float ov = z_lds[pb * 36 + 24 + pu] + xg3;
            float co = c_lds[pb * 8 + pu];
            float cn = sigm(fv) * co + sigm(iv) * tanh_(gv);
            float hn = sigm(ov) * tanh_(cn);
            c_lds[pb * 8 + pu] = cn;
            hrg[(nxt * BATCH + pb) * KHR + 64 + wg * 8 + pu] = f2b(hn);
            HsF[(size_t)(t * BATCH + pb) * 256 + wg * 8 + pu] = hn;
        }
        gridbar(bar, ++bar_phase);

        // ---- M phase: this wg owns batch b = wg ----
        hb[tid] = HsF[(size_t)(t * BATCH + wg) * 256 + tid];
        __syncthreads();
        // k GEMV: wave wid = k-part, lane = m
        {
            float a = 0.f;
#pragma unroll
            for (int i = 0; i < 8; ++i) {
                short8 w8 = *(const short8*)(wkeyT + lane * WKPAD + wid * 64 + i * 8);
#pragma unroll
                for (int e = 0; e < 8; ++e)
                    a += hb[wid * 64 + i * 8 + e] * b2f((u16)w8[e]);
            }
            kpart[wid * 64 + lane] = a;
        }
        // beta partial
        {
            float bp = hb[tid] * wbF[tid];
#pragma unroll
            for (int off = 32; off > 0; off >>= 1) bp += __shfl_xor(bp, off, 64);
            if (lane == 0) bred[wid] = bp;
        }
        __syncthreads();
        if (tid < 64) {   // finalize k, ||k||
            float kk = kpart[tid] + kpart[64 + tid] + kpart[128 + tid] + kpart[192 + tid];
            kv[tid] = kk;
            float k2 = kk * kk;
#pragma unroll
            for (int off = 32; off > 0; off >>= 1) k2 += __shfl_xor(k2, off, 64);
            if (tid == 0) sc[1] = sqrtf(k2);
        } else if (tid == 64) {   // beta = softplus
            float zb = bred[0] + bred[1] + bred[2] + bred[3];
            sc[0] = logf(1.f + __expf(zb));
        }
        __syncthreads();
        const float beta = sc[0], knorm = sc[1];

        // num + norm pass: thread = mem row
        float num = 0.f, nr2 = 0.f;
        {
            const float4* mrow = (const float4*)(memA + tid * MEMPAD);
            const float4* k4p  = (const float4*)kv;
#pragma unroll
            for (int i = 0; i < 16; ++i) {
                float4 m4 = mrow[i], k4 = k4p[i];
                num += m4.x * k4.x + m4.y * k4.y + m4.z * k4.z + m4.w * k4.w;
                nr2 += m4.x * m4.x + m4.y * m4.y + m4.z * m4.z + m4.w * m4.w;
            }
        }
        float den = fmaxf(sqrtf(nr2) * knorm, 1e-8f);
        float s   = beta * (num / den);
        // safe softmax over 256 rows
        float mx = s;
#pragma unroll
        for (int off = 32; off > 0; off >>= 1) mx = fmaxf(mx, __shfl_xor(mx, off, 64));
        if (lane == 0) wred[wid] = mx;
        __syncthreads();
        mx = fmaxf(fmaxf(wred[0], wred[1]), fmaxf(wred[2], wred[3]));
        float ev = __expf(s - mx);
        float ssum = ev;
#pragma unroll
        for (int off = 32; off > 0; off >>= 1) ssum += __shfl_xor(ssum, off, 64);
        if (lane == 0) wred[4 + wid] = ssum;
        __syncthreads();
        ssum = wred[4] + wred[5] + wred[6] + wred[7];
        float w = ev / ssum;
        wwts[tid] = w;
        __syncthreads();

        // fused update + read pass (quad mapping: 4 rows x 16 col-f4 per iter)
        {
            const int lm = lane & 15, q = lane >> 4;
            float4 k4 = ((const float4*)kv)[lm];
            float r0 = 0.f, r1 = 0.f, r2 = 0.f, r3 = 0.f;
#pragma unroll
            for (int i = 0; i < 16; ++i) {
                int n = wid * 64 + i * 4 + q;
                float wn = wwts[n];
                float4* mp = (float4*)(memA + n * MEMPAD + 4 * lm);
                float4 m4 = *mp;
                m4.x += wn * k4.x; m4.y += wn * k4.y; m4.z += wn * k4.z; m4.w += wn * k4.w;
                *mp = m4;
                r0 += wn * m4.x; r1 += wn * m4.y; r2 += wn * m4.z; r3 += wn * m4.w;
            }
            r0 += __shfl_xor(r0, 16, 64); r0 += __shfl_xor(r0, 32, 64);
            r1 += __shfl_xor(r1, 16, 64); r1 += __shfl_xor(r1, 32, 64);
            r2 += __shfl_xor(r2, 16, 64); r2 += __shfl_xor(r2, 32, 64);
            r3 += __shfl_xor(r3, 16, 64); r3 += __shfl_xor(r3, 32, 64);
            if (q == 0) {
                rp[wid * 64 + 4 * lm + 0] = r0;
                rp[wid * 64 + 4 * lm + 1] = r1;
                rp[wid * 64 + 4 * lm + 2] = r2;
                rp[wid * 64 + 4 * lm + 3] = r3;
            }
        }
        __syncthreads();
        if (tid < 64) {
            float rd = rp[tid] + rp[64 + tid] + rp[128 + tid] + rp[192 + tid];
            hrg[(nxt * BATCH + wg) * KHR + tid] = f2b(rd);
            RsF[(size_t)(t * BATCH + wg) * 64 + tid] = rd;
        }
        gridbar(bar, ++bar_phase);
    }
}

// ---------------- epilogue: ys = Hs@Wpre + Rs@Wro_eff + b_pre ; loss partials ----------------
__global__ void dnc_epilogue(char* __restrict__ ws, void* __restrict__ outv) {
    __shared__ float hs8[8][256];
    __shared__ float rs8[8][64];
    __shared__ float lacc;
    const float* HsF   = (const float*)(ws + WS_HS);
    const float* RsF   = (const float*)(ws + WS_RS);
    const float* WktF  = (const float*)(ws + WS_WKT);
    const float* WreF  = (const float*)(ws + WS_WROEFF);
    const float* WpreF = (const float*)(ws + WS_WPREF);
    const float* bpreF = (const float*)(ws + WS_BPREF);
    float* lossacc = (float*)(ws + WS_LOSS);
    const int bf = *(const int*)(ws + WS_FLAG);
    const int tid = threadIdx.x;
    const size_t r0 = (size_t)blockIdx.x * 8;
    if (tid == 0) lacc = 0.f;
    for (int i = tid; i < 8 * 256; i += 256) hs8[i >> 8][i & 255] = HsF[r0 * 256 + i];
    for (int i = tid; i < 8 * 64; i += 256)  rs8[i >> 6][i & 63]  = RsF[r0 * 64 + i];
    __syncthreads();
    // ys
    {
        const int rl = tid >> 5, c0 = (tid & 31) * 4;
        float a0 = bpreF[c0], a1 = bpreF[c0 + 1], a2 = bpreF[c0 + 2], a3 = bpreF[c0 + 3];
        for (int k = 0; k < 256; ++k) {
            float hv = hs8[rl][k];
            float4 w4 = *(const float4*)(WpreF + k * 128 + c0);
            a0 += hv * w4.x; a1 += hv * w4.y; a2 += hv * w4.z; a3 += hv * w4.w;
        }
        for (int m = 0; m < 64; ++m) {
            float rv = rs8[rl][m];
            float4 w4 = *(const float4*)(WreF + m * 128 + c0);
            a0 += rv * w4.x; a1 += rv * w4.y; a2 += rv * w4.z; a3 += rv * w4.w;
        }
        size_t o = (r0 + rl) * 128 + c0;
        if (bf) {
            u16* out = (u16*)outv;
            out[o] = f2b(a0); out[o + 1] = f2b(a1); out[o + 2] = f2b(a2); out[o + 3] = f2b(a3);
        } else {
            float* out = (float*)outv;
            out[o] = a0; out[o + 1] = a1; out[o + 2] = a2; out[o + 3] = a3;
        }
    }
    // loss: sum (h @ (Wkey - Wteach))^2
    {
        const int rl = tid >> 5, m0 = (tid & 31) * 2;
        float d0 = 0.f, d1 = 0.f;
        for (int k = 0; k < 256; ++k) {
            float hv = hs8[rl][k];
            d0 += hv * WktF[k * 64 + m0];
            d1 += hv * WktF[k * 64 + m0 + 1];
        }
        float p = d0 * d0 + d1 * d1;
#pragma unroll
        for (int off = 32; off > 0; off >>= 1) p += __shfl_xor(p, off, 64);
        if ((tid & 63) == 0) atomicAdd(&lacc, p);
        __syncthreads();
        if (tid == 0) atomicAdd(lossacc, lacc);
    }
}

__global__ void dnc_loss_fin(const char* __restrict__ ws, void* __restrict__ outv) {
    if (threadIdx.x == 0 && blockIdx.x == 0) {
        float l = *(const float*)(ws + WS_LOSS) * (1.f / 2048.f);
        if (*(const int*)(ws + WS_FLAG)) ((u16*)outv)[524288] = f2b(l);
        else                             ((float*)outv)[524288] = l;
    }
}

// ---------------- launch ----------------
extern "C" void kernel_launch(void* const* d_in, const int* in_sizes, int n_in,
                              void* d_out, int out_size, void* d_ws, size_t ws_size,
                              hipStream_t stream) {
    char* ws = (char*)d_ws;
    hipMemsetAsync(d_ws, 0, WS_ZSET, stream);   // barrier counter, loss acc, flag, hr buffers
    dnc_probe<<<1, 256, 0, stream>>>((const u16*)d_in[0], ws);
    dnc_normalize<<<1024, 256, 0, stream>>>(d_in[0], d_in[1], d_in[2], d_in[3], d_in[4],
                                            d_in[5], d_in[6], d_in[7], d_in[8], d_in[9], ws);
    dnc_prologue<<<1112, 256, 0, stream>>>(ws);
    hipFuncSetAttribute((const void*)dnc_main,
                        hipFuncAttributeMaxDynamicSharedMemorySize, LDS_TOTAL);
    dnc_main<<<32, 256, LDS_TOTAL, stream>>>(ws);
    dnc_epilogue<<<512, 256, 0, stream>>>(ws, d_out);
    dnc_loss_fin<<<1, 64, 0, stream>>>(ws, d_out);
}

// Round 3
// 1438.717 us; speedup vs baseline: 1.1405x; 1.1405x over previous
//
#include <hip/hip_runtime.h>

// ---------------- types / helpers ----------------
typedef unsigned short u16;
typedef unsigned long long u64;
typedef short short8 __attribute__((ext_vector_type(8)));
typedef float f32x4 __attribute__((ext_vector_type(4)));

__device__ __forceinline__ float b2f(u16 u) {
    unsigned x = ((unsigned)u) << 16;
    return __builtin_bit_cast(float, x);
}
__device__ __forceinline__ u16 f2b(float f) {
    unsigned u = __builtin_bit_cast(unsigned, f);
    u += 0x7FFFu + ((u >> 16) & 1u);   // RNE
    return (u16)(u >> 16);
}
__device__ __forceinline__ float sigm(float x) { return 1.f / (1.f + __expf(-x)); }
__device__ __forceinline__ float tanh_(float x) { return 1.f - 2.f / (__expf(2.f * x) + 1.f); }

// agent-scope (device-coherent) relaxed accesses — no cache-wide maintenance
__device__ __forceinline__ u64 ld_a_u64(const u16* p) {
    return __hip_atomic_load((const u64*)p, __ATOMIC_RELAXED, __HIP_MEMORY_SCOPE_AGENT);
}
__device__ __forceinline__ void st_a_u16(u16* p, u16 v) {
    __hip_atomic_store(p, v, __ATOMIC_RELAXED, __HIP_MEMORY_SCOPE_AGENT);
}

// ---------------- problem constants ----------------
#define T_STEPS 128
#define BATCH   32
#define KHR     320      // 64 (read) + 256 (h)
#define PADK    328      // hr_lds row pad (bf16 elems)
#define MEMPAD  68       // mem row stride in floats
#define WKPAD   264      // wkeyT row pad (bf16 elems)

// ---------------- workspace layout (bytes) ----------------
#define WS_BAR      0
#define WS_LOSS     64
#define WS_FLAG     96
#define WS_HRG      128                       // u16 [2][32][320] = 40960
#define WS_ZSET     41088                     // memset range end
// normalized fp32 inputs
#define WS_XSF      41216                     // 524288 f32
#define WS_MEM0F    2138368                   // 524288 f32
#define WS_WLF      4235520                   // 655360 f32
#define WS_BLF      6856960                   // 1024 f32
#define WS_WPREF    6861056                   // 32768 f32
#define WS_BPREF    6992128                   // 128 f32
#define WS_WKEYF    6992640                   // 16384 f32
#define WS_WBETAF   7058176                   // 256 f32
#define WS_WTEACHF  7059200                   // 16384 f32
#define WS_WROF     7124736                   // 32768 f32
// derived
#define WS_XW       7255808                   // f32 [4096][1024] = 16777216
#define WS_WREFF    24033024                  // f32 [64][1024]   = 262144
#define WS_WKT      24295168                  // f32 [256][64]    = 65536
#define WS_WROEFF   24360704                  // f32 [64][128]    = 32768
#define WS_HS       24393472                  // f32 [4096][256]  = 4194304
#define WS_RS       28587776                  // f32 [4096][64]   = 1048576
// total ~29.6 MB

// ---------------- LDS layout (bytes) ----------------
#define HR_OFF   0         // u16 [32][328]            20992
#define WF_OFF   20992     // u16 [10][4][32][8]       20480
#define WK_OFF   41472     // u16 [64][264]            33792
#define MEM_OFF  75264     // f32 [256][68]            69632
#define Z_OFF    144896    // f32 [32][36]             4608
#define C_OFF    149504    // f32 [32][8]              1024
#define HB_OFF   150528    // f32 [256]                1024
#define KV_OFF   151552    // f32 [64]                 256
#define WW_OFF   151808    // f32 [256]                1024
#define KP_OFF   152832    // f32 [4][64]              1024
#define RP_OFF   153856    // f32 [4][64]              1024
#define BR_OFF   154880    // f32 [16]
#define WR_OFF   154944    // f32 [16]
#define SC_OFF   155008    // f32 scalars
#define WB_OFF   155072    // f32 [256]                1024
#define LDS_TOTAL 156096

// ---------------- grid barrier (32 resident wgs), no cache maintenance ----------------
// __syncthreads drains each wave's vmcnt before s_barrier, so all agent-scope
// stores are at the coherence point before thread 0 increments.
__device__ __forceinline__ void gridbar(unsigned* bar, unsigned phase) {
    __syncthreads();
    if (threadIdx.x == 0) {
        __builtin_amdgcn_s_waitcnt(0);
        __hip_atomic_fetch_add(bar, 1u, __ATOMIC_RELAXED, __HIP_MEMORY_SCOPE_AGENT);
        const unsigned tgt = phase * 32u;
        long guard = 0;
        while (__hip_atomic_load(bar, __ATOMIC_RELAXED, __HIP_MEMORY_SCOPE_AGENT) < tgt) {
            __builtin_amdgcn_s_sleep(1);
            if (++guard > 3000000L) break;   // bail instead of hanging the bench
        }
    }
    __syncthreads();
}

// ---------------- dtype probe: f32 vs bf16 ----------------
__global__ void dnc_probe(const u16* __restrict__ xs_u16, char* __restrict__ ws) {
    __shared__ int cnt;
    if (threadIdx.x == 0) cnt = 0;
    __syncthreads();
    int c = 0;
    for (int i = threadIdx.x; i < 1024; i += 256) {
        int e = (xs_u16[i] >> 7) & 0xFF;
        if (e >= 96 && e <= 135) c++;
    }
    atomicAdd(&cnt, c);
    __syncthreads();
    if (threadIdx.x == 0) *(int*)(ws + WS_FLAG) = (cnt > 820) ? 1 : 0;   // 1 = bf16
}

// ---------------- normalize all inputs to fp32 in ws ----------------
__global__ void dnc_normalize(const void* s0, const void* s1, const void* s2, const void* s3,
                              const void* s4, const void* s5, const void* s6, const void* s7,
                              const void* s8, const void* s9, char* __restrict__ ws) {
    const void* srcs[10] = {s0, s1, s2, s3, s4, s5, s6, s7, s8, s9};
    const int sizes[10] = {524288, 524288, 655360, 1024, 32768, 128, 16384, 256, 16384, 32768};
    const int bases[10] = {WS_XSF, WS_MEM0F, WS_WLF, WS_BLF, WS_WPREF, WS_BPREF,
                           WS_WKEYF, WS_WBETAF, WS_WTEACHF, WS_WROF};
    const int bf = *(const int*)(ws + WS_FLAG);
    const int gt = blockIdx.x * 256 + threadIdx.x, gs = gridDim.x * 256;
    for (int s = 0; s < 10; ++s) {
        float* dst = (float*)(ws + bases[s]);
        const int n = sizes[s];
        if (bf) {
            const u16* p = (const u16*)srcs[s];
            for (int i = gt; i < n; i += gs) dst[i] = b2f(p[i]);
        } else {
            const float* p = (const float*)srcs[s];
            for (int i = gt; i < n; i += gs) dst[i] = p[i];
        }
    }
}

// ---------------- prologue: xW precompute + weight folds (fp32) ----------------
__global__ void dnc_prologue(char* __restrict__ ws) {
    const float* XSF     = (const float*)(ws + WS_XSF);
    const float* WLF     = (const float*)(ws + WS_WLF);
    const float* BLF     = (const float*)(ws + WS_BLF);
    const float* WKEYF   = (const float*)(ws + WS_WKEYF);
    const float* WTEACHF = (const float*)(ws + WS_WTEACHF);
    const float* WROF    = (const float*)(ws + WS_WROF);
    float* xW  = (float*)(ws + WS_XW);
    float* WrE = (float*)(ws + WS_WREFF);
    float* Wkt = (float*)(ws + WS_WKT);
    float* Wre = (float*)(ws + WS_WROEFF);
    const int wg = blockIdx.x, tid = threadIdx.x;
    if (wg < 1024) {
        // xW[r][c] = b_lstm[c] + sum_k X[r][k]*Wl[k][c]   (rows 0..127 of Wl)
        const int r  = wg * 4 + (tid >> 6);
        const int c0 = (tid & 63) * 16;
        float acc[16];
#pragma unroll
        for (int e = 0; e < 16; ++e) acc[e] = BLF[c0 + e];
        for (int k = 0; k < 128; ++k) {
            float xv = XSF[r * 128 + k];
            const float4* wr = (const float4*)(WLF + (size_t)k * 1024 + c0);
            float4 w0 = wr[0], w1 = wr[1], w2 = wr[2], w3 = wr[3];
            acc[0]  += xv * w0.x; acc[1]  += xv * w0.y; acc[2]  += xv * w0.z; acc[3]  += xv * w0.w;
            acc[4]  += xv * w1.x; acc[5]  += xv * w1.y; acc[6]  += xv * w1.z; acc[7]  += xv * w1.w;
            acc[8]  += xv * w2.x; acc[9]  += xv * w2.y; acc[10] += xv * w2.z; acc[11] += xv * w2.w;
            acc[12] += xv * w3.x; acc[13] += xv * w3.y; acc[14] += xv * w3.z; acc[15] += xv * w3.w;
        }
#pragma unroll
        for (int e = 0; e < 16; ++e) xW[(size_t)r * 1024 + c0 + e] = acc[e];
    } else if (wg < 1088) {
        // W_r_eff[m][c] = sum_{rr<4} W_lstm[128+4m+rr][c]  (rv index = m*4+r)
        const int m = wg - 1024;
        const int c = tid * 4;
#pragma unroll
        for (int e = 0; e < 4; ++e) {
            float s = 0.f;
#pragma unroll
            for (int rr = 0; rr < 4; ++rr) s += WLF[(size_t)(128 + 4 * m + rr) * 1024 + c + e];
            WrE[m * 1024 + c + e] = s;
        }
    } else if (wg < 1104) {
        // Wkt = Wkey - Wteach  [256][64]
        const int i = (wg - 1088) * 1024 + tid * 4;
#pragma unroll
        for (int e = 0; e < 4; ++e) Wkt[i + e] = WKEYF[i + e] - WTEACHF[i + e];
    } else if (wg < 1112) {
        // W_ro_eff[m][c] = sum_{rr<4} W_ro[4m+rr][c]
        const int i = (wg - 1104) * 1024 + tid * 4;
#pragma unroll
        for (int e = 0; e < 4; ++e) {
            int m = (i + e) >> 7, c = (i + e) & 127;
            float s = 0.f;
#pragma unroll
            for (int rr = 0; rr < 4; ++rr) s += WROF[(4 * m + rr) * 128 + c];
            Wre[i + e] = s;
        }
    }
}

// ---------------- main persistent kernel: 32 wgs, 2 grid barriers / step ----------------
__global__ __launch_bounds__(256, 1) void dnc_main(char* __restrict__ ws) {
    extern __shared__ char smem[];
    u16*   hr_lds = (u16*)(smem + HR_OFF);
    u16*   wfrag  = (u16*)(smem + WF_OFF);
    u16*   wkeyT  = (u16*)(smem + WK_OFF);
    float* memA   = (float*)(smem + MEM_OFF);
    float* z_lds  = (float*)(smem + Z_OFF);
    float* c_lds  = (float*)(smem + C_OFF);
    float* hb     = (float*)(smem + HB_OFF);
    float* kv     = (float*)(smem + KV_OFF);
    float* wwts   = (float*)(smem + WW_OFF);
    float* kpart  = (float*)(smem + KP_OFF);
    float* rp     = (float*)(smem + RP_OFF);
    float* bred   = (float*)(smem + BR_OFF);
    float* wred   = (float*)(smem + WR_OFF);
    float* sc     = (float*)(smem + SC_OFF);
    float* wbF    = (float*)(smem + WB_OFF);

    const int tid  = threadIdx.x;
    const int wg   = blockIdx.x;     // col-slice id AND batch id (0..31)
    const int lane = tid & 63;
    const int wid  = tid >> 6;       // wave 0..3

    unsigned* bar = (unsigned*)(ws + WS_BAR);
    u16* hrg      = (u16*)(ws + WS_HRG);               // [2][32][320] bf16
    const float* xWF     = (const float*)(ws + WS_XW);
    const float* WrEffF  = (const float*)(ws + WS_WREFF);
    const float* WLF     = (const float*)(ws + WS_WLF);
    const float* WKEYF   = (const float*)(ws + WS_WKEYF);
    const float* WBETAF  = (const float*)(ws + WS_WBETAF);
    const float* MEM0F   = (const float*)(ws + WS_MEM0F);
    float* HsF = (float*)(ws + WS_HS);
    float* RsF = (float*)(ws + WS_RS);

    // ---- one-time LDS init ----
    // wfrag[kt][q][c][j]: B-frag for MFMA; element k = kt*32+q*8+j, local col c = gate*8+u
    for (int idx = tid; idx < 10240; idx += 256) {
        int k = idx >> 5, c = idx & 31;
        int kt = k >> 5, q = (k >> 3) & 3, j = k & 7;
        int gcol = (c >> 3) * 256 + wg * 8 + (c & 7);
        float v = (k < 64) ? WrEffF[k * 1024 + gcol]
                           : WLF[(size_t)(384 + (k - 64)) * 1024 + gcol];
        wfrag[((kt * 4 + q) * 32 + c) * 8 + j] = f2b(v);
    }
    for (int i = tid; i < 256 * 64; i += 256) {   // wkeyT[m][k] = Wkey[k][m] (bf16)
        int k = i >> 6, m = i & 63;
        wkeyT[m * WKPAD + k] = f2b(WKEYF[i]);
    }
    wbF[tid]   = WBETAF[tid];
    c_lds[tid] = 0.f;
    for (int i = tid; i < 256 * 64; i += 256) {   // mem state fp32
        int n = i >> 6, m = i & 63;
        memA[n * MEMPAD + m] = MEM0F[wg * 16384 + i];
    }
    __syncthreads();

    const int bt = wid & 1, ct = wid >> 1;   // MFMA tile assignment
    const int fm = lane & 15, fq = lane >> 4;
    unsigned bar_phase = 0;

    for (int t = 0; t < T_STEPS; ++t) {
        const int cur = t & 1, nxt = cur ^ 1;

        // ---- Z: stage hr (all 32 batches) from global into padded LDS (agent loads) ----
        {
            const int b  = tid >> 3;
            const int k0 = (tid & 7) * 40;
            const u16* src = hrg + (cur * BATCH + b) * KHR + k0;
            u16* dst = hr_lds + b * PADK + k0;
#pragma unroll
            for (int i = 0; i < 5; ++i) {
                u64 lo = ld_a_u64(src + i * 8);
                u64 hi = ld_a_u64(src + i * 8 + 4);
                *(u64*)(dst + i * 8)     = lo;
                *(u64*)(dst + i * 8 + 4) = hi;
            }
        }
        // prefetch xW gate contributions (fp32, L2-resident)
        const int pb = tid >> 3, pu = tid & 7;
        const size_t xwbase = (size_t)(t * BATCH + pb) * 1024 + wg * 8 + pu;
        float xg0 = xWF[xwbase + 0];
        float xg1 = xWF[xwbase + 256];
        float xg2 = xWF[xwbase + 512];
        float xg3 = xWF[xwbase + 768];
        __syncthreads();

        // ---- MFMA: z[32b x 32cols] = hr(32x320) @ W'(320x32) ----
        f32x4 acc = {0.f, 0.f, 0.f, 0.f};
#pragma unroll
        for (int kt = 0; kt < 10; ++kt) {
            short8 a = *(const short8*)(hr_lds + (bt * 16 + fm) * PADK + kt * 32 + fq * 8);
            short8 b = *(const short8*)(wfrag + ((kt * 4 + fq) * 32 + ct * 16 + fm) * 8);
            acc = __builtin_amdgcn_mfma_f32_16x16x32_bf16(a, b, acc, 0, 0, 0);
        }
#pragma unroll
        for (int r = 0; r < 4; ++r) {
            int bb = bt * 16 + fq * 4 + r;        // C/D: row = quad*4+reg
            int cc = ct * 16 + fm;                //       col = lane&15
            z_lds[bb * 36 + cc] = acc[r];
        }
        __syncthreads();

        // ---- LSTM pointwise for hidden units [8*wg, 8*wg+8), all batches ----
        {
            float iv = z_lds[pb * 36 + pu]      + xg0;
            float fv = z_lds[pb * 36 + 8 + pu]  + xg1;
            float gv = z_lds[pb * 36 + 16 + pu] + xg2;
            float ov = z_lds[pb * 36 + 24 + pu] + xg3;
            float co = c_lds[pb * 8 + pu];
            float cn = sigm(fv) * co + sigm(iv) * tanh_(gv);
            float hn = sigm(ov) * tanh_(cn);
            c_lds[pb * 8 + pu] = cn;
            st_a_u16(hrg + (nxt * BATCH + pb) * KHR + 64 + wg * 8 + pu, f2b(hn));
            HsF[(size_t)(t * BATCH + pb) * 256 + wg * 8 + pu] = hn;   // epilogue-only
        }
        gridbar(bar, ++bar_phase);

        // ---- M phase: this wg owns batch b = wg ----
        if (tid < 64) {
            u64 v = ld_a_u64(hrg + (nxt * BATCH + wg) * KHR + 64 + tid * 4);
            hb[tid * 4 + 0] = b2f((u16)(v));
            hb[tid * 4 + 1] = b2f((u16)(v >> 16));
            hb[tid * 4 + 2] = b2f((u16)(v >> 32));
            hb[tid * 4 + 3] = b2f((u16)(v >> 48));
        }
        __syncthreads();
        // k GEMV: wave wid = k-part, lane = m
        {
            float a = 0.f;
#pragma unroll
            for (int i = 0; i < 8; ++i) {
                short8 w8 = *(const short8*)(wkeyT + lane * WKPAD + wid * 64 + i * 8);
#pragma unroll
                for (int e = 0; e < 8; ++e)
                    a += hb[wid * 64 + i * 8 + e] * b2f((u16)w8[e]);
            }
            kpart[wid * 64 + lane] = a;
        }
        // beta partial
        {
            float bp = hb[tid] * wbF[tid];
#pragma unroll
            for (int off = 32; off > 0; off >>= 1) bp += __shfl_xor(bp, off, 64);
            if (lane == 0) bred[wid] = bp;
        }
        __syncthreads();
        if (tid < 64) {   // finalize k, ||k||
            float kk = kpart[tid] + kpart[64 + tid] + kpart[128 + tid] + kpart[192 + tid];
            kv[tid] = kk;
            float k2 = kk * kk;
#pragma unroll
            for (int off = 32; off > 0; off >>= 1) k2 += __shfl_xor(k2, off, 64);
            if (tid == 0) sc[1] = sqrtf(k2);
        } else if (tid == 64) {   // beta = softplus
            float zb = bred[0] + bred[1] + bred[2] + bred[3];
            sc[0] = logf(1.f + __expf(zb));
        }
        __syncthreads();
        const float beta = sc[0], knorm = sc[1];

        // num + norm pass: thread = mem row
        float num = 0.f, nr2 = 0.f;
        {
            const float4* mrow = (const float4*)(memA + tid * MEMPAD);
            const float4* k4p  = (const float4*)kv;
#pragma unroll
            for (int i = 0; i < 16; ++i) {
                float4 m4 = mrow[i], k4 = k4p[i];
                num += m4.x * k4.x + m4.y * k4.y + m4.z * k4.z + m4.w * k4.w;
                nr2 += m4.x * m4.x + m4.y * m4.y + m4.z * m4.z + m4.w * m4.w;
            }
        }
        float den = fmaxf(sqrtf(nr2) * knorm, 1e-8f);
        float s   = beta * (num / den);
        // safe softmax over 256 rows
        float mx = s;
#pragma unroll
        for (int off = 32; off > 0; off >>= 1) mx = fmaxf(mx, __shfl_xor(mx, off, 64));
        if (lane == 0) wred[wid] = mx;
        __syncthreads();
        mx = fmaxf(fmaxf(wred[0], wred[1]), fmaxf(wred[2], wred[3]));
        float ev = __expf(s - mx);
        float ssum = ev;
#pragma unroll
        for (int off = 32; off > 0; off >>= 1) ssum += __shfl_xor(ssum, off, 64);
        if (lane == 0) wred[4 + wid] = ssum;
        __syncthreads();
        ssum = wred[4] + wred[5] + wred[6] + wred[7];
        float w = ev / ssum;
        wwts[tid] = w;
        __syncthreads();

        // fused update + read pass (quad mapping: 4 rows x 16 col-f4 per iter)
        {
            const int lm = lane & 15, q = lane >> 4;
            float4 k4 = ((const float4*)kv)[lm];
            float r0 = 0.f, r1 = 0.f, r2 = 0.f, r3 = 0.f;
#pragma unroll
            for (int i = 0; i < 16; ++i) {
                int n = wid * 64 + i * 4 + q;
                float wn = wwts[n];
                float4* mp = (float4*)(memA + n * MEMPAD + 4 * lm);
                float4 m4 = *mp;
                m4.x += wn * k4.x; m4.y += wn * k4.y; m4.z += wn * k4.z; m4.w += wn * k4.w;
                *mp = m4;
                r0 += wn * m4.x; r1 += wn * m4.y; r2 += wn * m4.z; r3 += wn * m4.w;
            }
            r0 += __shfl_xor(r0, 16, 64); r0 += __shfl_xor(r0, 32, 64);
            r1 += __shfl_xor(r1, 16, 64); r1 += __shfl_xor(r1, 32, 64);
            r2 += __shfl_xor(r2, 16, 64); r2 += __shfl_xor(r2, 32, 64);
            r3 += __shfl_xor(r3, 16, 64); r3 += __shfl_xor(r3, 32, 64);
            if (q == 0) {
                rp[wid * 64 + 4 * lm + 0] = r0;
                rp[wid * 64 + 4 * lm + 1] = r1;
                rp[wid * 64 + 4 * lm + 2] = r2;
                rp[wid * 64 + 4 * lm + 3] = r3;
            }
        }
        __syncthreads();
        if (tid < 64) {
            float rd = rp[tid] + rp[64 + tid] + rp[128 + tid] + rp[192 + tid];
            st_a_u16(hrg + (nxt * BATCH + wg) * KHR + tid, f2b(rd));
            RsF[(size_t)(t * BATCH + wg) * 64 + tid] = rd;   // epilogue-only
        }
        gridbar(bar, ++bar_phase);
    }
}

// ---------------- epilogue: ys = Hs@Wpre + Rs@Wro_eff + b_pre ; loss partials ----------------
__global__ void dnc_epilogue(char* __restrict__ ws, void* __restrict__ outv) {
    __shared__ float hs8[8][256];
    __shared__ float rs8[8][64];
    __shared__ float lacc;
    const float* HsF   = (const float*)(ws + WS_HS);
    const float* RsF   = (const float*)(ws + WS_RS);
    const float* WktF  = (const float*)(ws + WS_WKT);
    const float* WreF  = (const float*)(ws + WS_WROEFF);
    const float* WpreF = (const float*)(ws + WS_WPREF);
    const float* bpreF = (const float*)(ws + WS_BPREF);
    float* lossacc = (float*)(ws + WS_LOSS);
    const int bf = *(const int*)(ws + WS_FLAG);
    const int tid = threadIdx.x;
    const size_t r0 = (size_t)blockIdx.x * 8;
    if (tid == 0) lacc = 0.f;
    for (int i = tid; i < 8 * 256; i += 256) hs8[i >> 8][i & 255] = HsF[r0 * 256 + i];
    for (int i = tid; i < 8 * 64; i += 256)  rs8[i >> 6][i & 63]  = RsF[r0 * 64 + i];
    __syncthreads();
    // ys
    {
        const int rl = tid >> 5, c0 = (tid & 31) * 4;
        float a0 = bpreF[c0], a1 = bpreF[c0 + 1], a2 = bpreF[c0 + 2], a3 = bpreF[c0 + 3];
        for (int k = 0; k < 256; ++k) {
            float hv = hs8[rl][k];
            float4 w4 = *(const float4*)(WpreF + k * 128 + c0);
            a0 += hv * w4.x; a1 += hv * w4.y; a2 += hv * w4.z; a3 += hv * w4.w;
        }
        for (int m = 0; m < 64; ++m) {
            float rv = rs8[rl][m];
            float4 w4 = *(const float4*)(WreF + m * 128 + c0);
            a0 += rv * w4.x; a1 += rv * w4.y; a2 += rv * w4.z; a3 += rv * w4.w;
        }
        size_t o = (r0 + rl) * 128 + c0;
        if (bf) {
            u16* out = (u16*)outv;
            out[o] = f2b(a0); out[o + 1] = f2b(a1); out[o + 2] = f2b(a2); out[o + 3] = f2b(a3);
        } else {
            float* out = (float*)outv;
            out[o] = a0; out[o + 1] = a1; out[o + 2] = a2; out[o + 3] = a3;
        }
    }
    // loss: sum (h @ (Wkey - Wteach))^2
    {
        const int rl = tid >> 5, m0 = (tid & 31) * 2;
        float d0 = 0.f, d1 = 0.f;
        for (int k = 0; k < 256; ++k) {
            float hv = hs8[rl][k];
            d0 += hv * WktF[k * 64 + m0];
            d1 += hv * WktF[k * 64 + m0 + 1];
        }
        float p = d0 * d0 + d1 * d1;
#pragma unroll
        for (int off = 32; off > 0; off >>= 1) p += __shfl_xor(p, off, 64);
        if ((tid & 63) == 0) atomicAdd(&lacc, p);
        __syncthreads();
        if (tid == 0) atomicAdd(lossacc, lacc);
    }
}

__global__ void dnc_loss_fin(const char* __restrict__ ws, void* __restrict__ outv) {
    if (threadIdx.x == 0 && blockIdx.x == 0) {
        float l = *(const float*)(ws + WS_LOSS) * (1.f / 2048.f);
        if (*(const int*)(ws + WS_FLAG)) ((u16*)outv)[524288] = f2b(l);
        else                             ((float*)outv)[524288] = l;
    }
}

// ---------------- launch ----------------
extern "C" void kernel_launch(void* const* d_in, const int* in_sizes, int n_in,
                              void* d_out, int out_size, void* d_ws, size_t ws_size,
                              hipStream_t stream) {
    char* ws = (char*)d_ws;
    hipMemsetAsync(d_ws, 0, WS_ZSET, stream);   // barrier counter, loss acc, flag, hr buffers
    dnc_probe<<<1, 256, 0, stream>>>((const u16*)d_in[0], ws);
    dnc_normalize<<<1024, 256, 0, stream>>>(d_in[0], d_in[1], d_in[2], d_in[3], d_in[4],
                                            d_in[5], d_in[6], d_in[7], d_in[8], d_in[9], ws);
    dnc_prologue<<<1112, 256, 0, stream>>>(ws);
    hipFuncSetAttribute((const void*)dnc_main,
                        hipFuncAttributeMaxDynamicSharedMemorySize, LDS_TOTAL);
    dnc_main<<<32, 256, LDS_TOTAL, stream>>>(ws);
    dnc_epilogue<<<512, 256, 0, stream>>>(ws, d_out);
    dnc_loss_fin<<<1, 64, 0, stream>>>(ws, d_out);
}

// Round 5
// 1243.163 us; speedup vs baseline: 1.3199x; 1.1573x over previous
//
#include <hip/hip_runtime.h>

// ---------------- types / helpers ----------------
typedef unsigned short u16;
typedef unsigned long long u64;
typedef short short8 __attribute__((ext_vector_type(8)));
typedef float f32x4 __attribute__((ext_vector_type(4)));

__device__ __forceinline__ float b2f(u16 u) {
    unsigned x = ((unsigned)u) << 16;
    return __builtin_bit_cast(float, x);
}
__device__ __forceinline__ u16 f2b(float f) {
    unsigned u = __builtin_bit_cast(unsigned, f);
    u += 0x7FFFu + ((u >> 16) & 1u);   // RNE
    return (u16)(u >> 16);
}
__device__ __forceinline__ float sigm(float x) { return 1.f / (1.f + __expf(-x)); }
__device__ __forceinline__ float tanh_(float x) { return 1.f - 2.f / (__expf(2.f * x) + 1.f); }

// ---- coherent (L1+L2-bypass) accesses ----
// loads: inline asm (struct OUTPUT operands are supported), waitcnt fused
__device__ __forceinline__ uint4 ldg_cv(const void* p) {
    uint4 v;
    asm volatile("global_load_dwordx4 %0, %1, off sc0 sc1\n\ts_waitcnt vmcnt(0)"
                 : "=v"(v) : "v"(p) : "memory");
    return v;
}
__device__ __forceinline__ void ldg_cv4(const void* p0, const void* p1, const void* p2,
                                        const void* p3, uint4& a, uint4& b, uint4& c, uint4& d) {
    asm volatile(
        "global_load_dwordx4 %0, %4, off sc0 sc1\n\t"
        "global_load_dwordx4 %1, %5, off sc0 sc1\n\t"
        "global_load_dwordx4 %2, %6, off sc0 sc1\n\t"
        "global_load_dwordx4 %3, %7, off sc0 sc1\n\t"
        "s_waitcnt vmcnt(0)"
        : "=v"(a), "=v"(b), "=v"(c), "=v"(d)
        : "v"(p0), "v"(p1), "v"(p2), "v"(p3) : "memory");
}
// stores: struct asm INPUTS unsupported -> two relaxed agent-scope u64 atomic stores
__device__ __forceinline__ void stg_cv(void* p, uint4 v) {
    u64 lo = ((u64)v.y << 32) | (u64)v.x;
    u64 hi = ((u64)v.w << 32) | (u64)v.z;
    __hip_atomic_store((u64*)p,     lo, __ATOMIC_RELAXED, __HIP_MEMORY_SCOPE_AGENT);
    __hip_atomic_store((u64*)p + 1, hi, __ATOMIC_RELAXED, __HIP_MEMORY_SCOPE_AGENT);
}

// ---------------- problem constants ----------------
#define T_STEPS 128
#define BATCH   32
#define KHR     320      // 64 (read) + 256 (h)
#define PADK    328      // hr_lds row pad (bf16 elems)
#define MEMPAD  68       // mem row stride in floats
#define WKPAD   264      // wkeyT row pad (bf16 elems)

// ---------------- workspace layout (bytes) ----------------
#define WS_BAR      0
#define WS_LOSS     64
#define WS_FLAG     96
#define WS_HRG      128                       // u16 [32][320] = 20480 (single buffer)
#define WS_ZSET     41088                     // memset range end
// normalized fp32 inputs
#define WS_XSF      41216                     // 524288 f32
#define WS_MEM0F    2138368                   // 524288 f32
#define WS_WLF      4235520                   // 655360 f32
#define WS_BLF      6856960                   // 1024 f32
#define WS_WPREF    6861056                   // 32768 f32
#define WS_BPREF    6992128                   // 128 f32
#define WS_WKEYF    6992640                   // 16384 f32
#define WS_WBETAF   7058176                   // 256 f32
#define WS_WTEACHF  7059200                   // 16384 f32
#define WS_WROF     7124736                   // 32768 f32
// derived
#define WS_XW       7255808                   // f32 [4096][1024] = 16777216
#define WS_WREFF    24033024                  // f32 [64][1024]   = 262144
#define WS_WKT      24295168                  // f32 [256][64]    = 65536
#define WS_WROEFF   24360704                  // f32 [64][128]    = 32768
#define WS_HS       24393472                  // f32 [4096][256]  = 4194304
#define WS_RS       28587776                  // f32 [4096][64]   = 1048576

// ---------------- LDS layout (bytes) ----------------
#define HR_OFF   0         // u16 [32][328]            20992
#define WF_OFF   20992     // u16 [10][4][32][8]       20480
#define WK_OFF   41472     // u16 [64][264]            33792
#define MEM_OFF  75264     // f32 [256][68]            69632
#define Z_OFF    144896    // f32 [32][36]             4608
#define C_OFF    149504    // f32 [32][8]              1024
#define KV_OFF   151552    // f32 [64]                 256
#define WW_OFF   151808    // f32 [256]                1024
#define KP_OFF   152832    // f32 [4][64]              1024
#define RP_OFF   153856    // f32 [4][64]              1024
#define BR_OFF   154880    // f32 [16]
#define WR_OFF   154944    // f32 [16]
#define SC_OFF   155008    // f32 scalars
#define WB_OFF   155072    // f32 [256]                1024
#define HST_OFF  156096    // u16 [256]                512
#define RST_OFF  156608    // u16 [64]                 128
#define LDS_TOTAL 156736

// ---------------- grid barrier (32 resident wgs) ----------------
__device__ __forceinline__ void gridbar(unsigned* bar, unsigned phase) {
    __syncthreads();
    if (threadIdx.x == 0) {
        __builtin_amdgcn_s_waitcnt(0);
        __hip_atomic_fetch_add(bar, 1u, __ATOMIC_RELAXED, __HIP_MEMORY_SCOPE_AGENT);
        const unsigned tgt = phase * 32u;
        long guard = 0;
        while (__hip_atomic_load(bar, __ATOMIC_RELAXED, __HIP_MEMORY_SCOPE_AGENT) < tgt) {
            __builtin_amdgcn_s_sleep(1);
            if (++guard > 3000000L) break;   // bail instead of hanging the bench
        }
    }
    __syncthreads();
}

// ---------------- dtype probe: f32 vs bf16 ----------------
__global__ void dnc_probe(const u16* __restrict__ xs_u16, char* __restrict__ ws) {
    __shared__ int cnt;
    if (threadIdx.x == 0) cnt = 0;
    __syncthreads();
    int c = 0;
    for (int i = threadIdx.x; i < 1024; i += 256) {
        int e = (xs_u16[i] >> 7) & 0xFF;
        if (e >= 96 && e <= 135) c++;
    }
    atomicAdd(&cnt, c);
    __syncthreads();
    if (threadIdx.x == 0) *(int*)(ws + WS_FLAG) = (cnt > 820) ? 1 : 0;   // 1 = bf16
}

// ---------------- normalize all inputs to fp32 in ws ----------------
__global__ void dnc_normalize(const void* s0, const void* s1, const void* s2, const void* s3,
                              const void* s4, const void* s5, const void* s6, const void* s7,
                              const void* s8, const void* s9, char* __restrict__ ws) {
    const void* srcs[10] = {s0, s1, s2, s3, s4, s5, s6, s7, s8, s9};
    const int sizes[10] = {524288, 524288, 655360, 1024, 32768, 128, 16384, 256, 16384, 32768};
    const int bases[10] = {WS_XSF, WS_MEM0F, WS_WLF, WS_BLF, WS_WPREF, WS_BPREF,
                           WS_WKEYF, WS_WBETAF, WS_WTEACHF, WS_WROF};
    const int bf = *(const int*)(ws + WS_FLAG);
    const int gt = blockIdx.x * 256 + threadIdx.x, gs = gridDim.x * 256;
    for (int s = 0; s < 10; ++s) {
        float* dst = (float*)(ws + bases[s]);
        const int n = sizes[s];
        if (bf) {
            const u16* p = (const u16*)srcs[s];
            for (int i = gt; i < n; i += gs) dst[i] = b2f(p[i]);
        } else {
            const float* p = (const float*)srcs[s];
            for (int i = gt; i < n; i += gs) dst[i] = p[i];
        }
    }
}

// ---------------- prologue: xW 2D-blocked GEMM + weight folds (fp32) ----------------
// wg < 256: 128x128 tile of xW = xs(4096x128) @ Wl[0:128](128x1024) + b.
// wg 256..319: WrEff fold; 320..335: Wkt; 336..343: WroEff.
__global__ void dnc_prologue(char* __restrict__ ws) {
    extern __shared__ float xls[];   // [128][129]
    const float* XSF     = (const float*)(ws + WS_XSF);
    const float* WLF     = (const float*)(ws + WS_WLF);
    const float* BLF     = (const float*)(ws + WS_BLF);
    const float* WKEYF   = (const float*)(ws + WS_WKEYF);
    const float* WTEACHF = (const float*)(ws + WS_WTEACHF);
    const float* WROF    = (const float*)(ws + WS_WROF);
    float* xW  = (float*)(ws + WS_XW);
    float* WrE = (float*)(ws + WS_WREFF);
    float* Wkt = (float*)(ws + WS_WKT);
    float* Wre = (float*)(ws + WS_WROEFF);
    const int wg = blockIdx.x, tid = threadIdx.x;
    if (wg < 256) {
        const int rb = wg >> 3, cb = wg & 7;
        const float4* xsrc = (const float4*)(XSF + (size_t)rb * 16384);
        for (int i = tid; i < 4096; i += 256) {
            float4 v = xsrc[i];
            int row = i >> 5, c4 = (i & 31) * 4;
            float* d = xls + row * 129 + c4;
            d[0] = v.x; d[1] = v.y; d[2] = v.z; d[3] = v.w;
        }
        __syncthreads();
        const int tr = tid >> 4, tc = tid & 15;
        const int c0 = cb * 128 + tc * 8;
        float acc[8][8];
#pragma unroll
        for (int rr = 0; rr < 8; ++rr)
#pragma unroll
            for (int cc = 0; cc < 8; ++cc) acc[rr][cc] = BLF[c0 + cc];
        for (int k = 0; k < 128; ++k) {
            float4 wA = *(const float4*)(WLF + (size_t)k * 1024 + c0);
            float4 wB = *(const float4*)(WLF + (size_t)k * 1024 + c0 + 4);
            float w[8] = {wA.x, wA.y, wA.z, wA.w, wB.x, wB.y, wB.z, wB.w};
#pragma unroll
            for (int rr = 0; rr < 8; ++rr) {
                float xv = xls[(tr * 8 + rr) * 129 + k];
#pragma unroll
                for (int cc = 0; cc < 8; ++cc) acc[rr][cc] += xv * w[cc];
            }
        }
#pragma unroll
        for (int rr = 0; rr < 8; ++rr) {
            size_t o = (size_t)(rb * 128 + tr * 8 + rr) * 1024 + c0;
            *(float4*)(xW + o)     = make_float4(acc[rr][0], acc[rr][1], acc[rr][2], acc[rr][3]);
            *(float4*)(xW + o + 4) = make_float4(acc[rr][4], acc[rr][5], acc[rr][6], acc[rr][7]);
        }
    } else if (wg < 320) {
        const int m = wg - 256;
        const int c = tid * 4;
#pragma unroll
        for (int e = 0; e < 4; ++e) {
            float s = 0.f;
#pragma unroll
            for (int rr = 0; rr < 4; ++rr) s += WLF[(size_t)(128 + 4 * m + rr) * 1024 + c + e];
            WrE[m * 1024 + c + e] = s;
        }
    } else if (wg < 336) {
        const int i = (wg - 320) * 1024 + tid * 4;
#pragma unroll
        for (int e = 0; e < 4; ++e) Wkt[i + e] = WKEYF[i + e] - WTEACHF[i + e];
    } else if (wg < 344) {
        const int i = (wg - 336) * 1024 + tid * 4;
#pragma unroll
        for (int e = 0; e < 4; ++e) {
            int m = (i + e) >> 7, c = (i + e) & 127;
            float s = 0.f;
#pragma unroll
            for (int rr = 0; rr < 4; ++rr) s += WROF[(4 * m + rr) * 128 + c];
            Wre[i + e] = s;
        }
    }
}

// ---------------- main persistent kernel: 32 wgs, 2 grid barriers / step ----------------
__global__ __launch_bounds__(256, 1) void dnc_main(char* __restrict__ ws) {
    extern __shared__ char smem[];
    u16*   hr_lds = (u16*)(smem + HR_OFF);
    u16*   wfrag  = (u16*)(smem + WF_OFF);
    u16*   wkeyT  = (u16*)(smem + WK_OFF);
    float* memA   = (float*)(smem + MEM_OFF);
    float* z_lds  = (float*)(smem + Z_OFF);
    float* c_lds  = (float*)(smem + C_OFF);
    float* kv     = (float*)(smem + KV_OFF);
    float* wwts   = (float*)(smem + WW_OFF);
    float* kpart  = (float*)(smem + KP_OFF);
    float* rp     = (float*)(smem + RP_OFF);
    float* bred   = (float*)(smem + BR_OFF);
    float* wred   = (float*)(smem + WR_OFF);
    float* sc     = (float*)(smem + SC_OFF);
    float* wbF    = (float*)(smem + WB_OFF);
    u16*   hstage = (u16*)(smem + HST_OFF);
    u16*   rstage = (u16*)(smem + RST_OFF);

    const int tid  = threadIdx.x;
    const int wg   = blockIdx.x;     // col-slice id AND batch id (0..31)
    const int lane = tid & 63;
    const int wid  = tid >> 6;       // wave 0..3

    unsigned* bar = (unsigned*)(ws + WS_BAR);
    u16* hrg      = (u16*)(ws + WS_HRG);               // [32][320] bf16, single buffer
    const float* xWF     = (const float*)(ws + WS_XW);
    const float* WrEffF  = (const float*)(ws + WS_WREFF);
    const float* WLF     = (const float*)(ws + WS_WLF);
    const float* WKEYF   = (const float*)(ws + WS_WKEYF);
    const float* WBETAF  = (const float*)(ws + WS_WBETAF);
    const float* MEM0F   = (const float*)(ws + WS_MEM0F);
    float* HsF = (float*)(ws + WS_HS);
    float* RsF = (float*)(ws + WS_RS);

    // ---- one-time LDS init ----
    for (int i = tid; i < 32 * PADK; i += 256) hr_lds[i] = 0;   // h(-1)=0, r(-1)=0
    for (int idx = tid; idx < 10240; idx += 256) {
        int k = idx >> 5, c = idx & 31;
        int kt = k >> 5, q = (k >> 3) & 3, j = k & 7;
        int gcol = (c >> 3) * 256 + wg * 8 + (c & 7);
        float v = (k < 64) ? WrEffF[k * 1024 + gcol]
                           : WLF[(size_t)(384 + (k - 64)) * 1024 + gcol];
        wfrag[((kt * 4 + q) * 32 + c) * 8 + j] = f2b(v);
    }
    for (int i = tid; i < 256 * 64; i += 256) {   // wkeyT[m][k] = Wkey[k][m] (bf16)
        int k = i >> 6, m = i & 63;
        wkeyT[m * WKPAD + k] = f2b(WKEYF[i]);
    }
    wbF[tid]   = WBETAF[tid];
    c_lds[tid] = 0.f;
    for (int i = tid; i < 256 * 64; i += 256) {   // mem state fp32
        int n = i >> 6, m = i & 63;
        memA[n * MEMPAD + m] = MEM0F[wg * 16384 + i];
    }
    __syncthreads();

    const int bt = wid & 1, ct = wid >> 1;   // MFMA tile assignment
    const int fm = lane & 15, fq = lane >> 4;
    const int pb = tid >> 3, pu = tid & 7;   // batch / unit for pointwise & staging
    unsigned bar_phase = 0;

    // preload xW gate contributions for t=0
    float xg0, xg1, xg2, xg3;
    {
        const size_t xb = (size_t)pb * 1024 + wg * 8 + pu;
        xg0 = xWF[xb]; xg1 = xWF[xb + 256]; xg2 = xWF[xb + 512]; xg3 = xWF[xb + 768];
    }

    for (int t = 0; t < T_STEPS; ++t) {
        // ---- Z: stage r(t-1) only (h(t-1) already in hr_lds via M-phase prefetch) ----
        {
            uint4 rv = ldg_cv(hrg + pb * KHR + pu * 8);          // 16B of r
            *(uint4*)(hr_lds + pb * PADK + pu * 8) = rv;
        }
        __syncthreads();

        // ---- MFMA: z[32b x 32cols] = hr(32x320) @ W'(320x32) ----
        f32x4 acc = {0.f, 0.f, 0.f, 0.f};
#pragma unroll
        for (int kt = 0; kt < 10; ++kt) {
            short8 a = *(const short8*)(hr_lds + (bt * 16 + fm) * PADK + kt * 32 + fq * 8);
            short8 b = *(const short8*)(wfrag + ((kt * 4 + fq) * 32 + ct * 16 + fm) * 8);
            acc = __builtin_amdgcn_mfma_f32_16x16x32_bf16(a, b, acc, 0, 0, 0);
        }
#pragma unroll
        for (int r = 0; r < 4; ++r) {
            int bb = bt * 16 + fq * 4 + r;        // C/D: row = quad*4+reg
            int cc = ct * 16 + fm;                //       col = lane&15
            z_lds[bb * 36 + cc] = acc[r];
        }
        __syncthreads();

        // ---- LSTM pointwise for hidden units [8*wg, 8*wg+8), all batches ----
        {
            float iv = z_lds[pb * 36 + pu]      + xg0;
            float fv = z_lds[pb * 36 + 8 + pu]  + xg1;
            float gv = z_lds[pb * 36 + 16 + pu] + xg2;
            float ov = z_lds[pb * 36 + 24 + pu] + xg3;
            float co = c_lds[pb * 8 + pu];
            float cn = sigm(fv) * co + sigm(iv) * tanh_(gv);
            float hn = sigm(ov) * tanh_(cn);
            c_lds[pb * 8 + pu] = cn;
            hstage[pb * 8 + pu] = f2b(hn);
            HsF[(size_t)(t * BATCH + pb) * 256 + wg * 8 + pu] = hn;   // epilogue-only
        }
        __syncthreads();
        if (tid < 32) {   // packed coherent h store: 16B per batch row
            uint4 hv = *(const uint4*)(hstage + tid * 8);
            stg_cv(hrg + tid * KHR + 64 + wg * 8, hv);
        }
        gridbar(bar, ++bar_phase);

        // ---- M phase. First: prefetch h(t) (final since barrier1) into hr_lds for Z(t+1) ----
        {
            const u16* src = hrg + pb * KHR + 64 + pu * 32;
            uint4 a, b, c, d;
            ldg_cv4(src, src + 8, src + 16, src + 24, a, b, c, d);
            u16* dst = hr_lds + pb * PADK + 64 + pu * 32;
            *(uint4*)(dst)      = a;
            *(uint4*)(dst + 8)  = b;
            *(uint4*)(dst + 16) = c;
            *(uint4*)(dst + 24) = d;
        }
        // prefetch xW gates for t+1 (plain cached loads; land during M phase)
        {
            int tn = (t + 1 < T_STEPS) ? t + 1 : 127;
            const size_t xb = (size_t)(tn * BATCH + pb) * 1024 + wg * 8 + pu;
            xg0 = xWF[xb]; xg1 = xWF[xb + 256]; xg2 = xWF[xb + 512]; xg3 = xWF[xb + 768];
        }
        __syncthreads();

        // this wg owns batch b = wg; h_b now in hr_lds[wg]
        const u16* hrow = hr_lds + wg * PADK + 64;
        // k GEMV: wave wid = k-part, lane = m
        {
            float a = 0.f;
#pragma unroll
            for (int i = 0; i < 8; ++i) {
                short8 w8 = *(const short8*)(wkeyT + lane * WKPAD + wid * 64 + i * 8);
                short8 h8 = *(const short8*)(hrow + wid * 64 + i * 8);
#pragma unroll
                for (int e = 0; e < 8; ++e)
                    a += b2f((u16)h8[e]) * b2f((u16)w8[e]);
            }
            kpart[wid * 64 + lane] = a;
        }
        // beta partial
        {
            float bp = b2f(hrow[tid]) * wbF[tid];
#pragma unroll
            for (int off = 32; off > 0; off >>= 1) bp += __shfl_xor(bp, off, 64);
            if (lane == 0) bred[wid] = bp;
        }
        __syncthreads();
        if (tid < 64) {   // finalize k, ||k||
            float kk = kpart[tid] + kpart[64 + tid] + kpart[128 + tid] + kpart[192 + tid];
            kv[tid] = kk;
            float k2 = kk * kk;
#pragma unroll
            for (int off = 32; off > 0; off >>= 1) k2 += __shfl_xor(k2, off, 64);
            if (tid == 0) sc[1] = sqrtf(k2);
        } else if (tid == 64) {   // beta = softplus
            float zb = bred[0] + bred[1] + bred[2] + bred[3];
            sc[0] = logf(1.f + __expf(zb));
        }
        __syncthreads();
        const float beta = sc[0], knorm = sc[1];

        // num + norm pass: thread = mem row
        float num = 0.f, nr2 = 0.f;
        {
            const float4* mrow = (const float4*)(memA + tid * MEMPAD);
            const float4* k4p  = (const float4*)kv;
#pragma unroll
            for (int i = 0; i < 16; ++i) {
                float4 m4 = mrow[i], k4 = k4p[i];
                num += m4.x * k4.x + m4.y * k4.y + m4.z * k4.z + m4.w * k4.w;
                nr2 += m4.x * m4.x + m4.y * m4.y + m4.z * m4.z + m4.w * m4.w;
            }
        }
        float den = fmaxf(sqrtf(nr2) * knorm, 1e-8f);
        float s   = beta * (num / den);
        // single-pass per-wave max+sumexp, then combine
        float wm = s;
#pragma unroll
        for (int off = 32; off > 0; off >>= 1) wm = fmaxf(wm, __shfl_xor(wm, off, 64));
        float ev = __expf(s - wm);
        float wsum = ev;
#pragma unroll
        for (int off = 32; off > 0; off >>= 1) wsum += __shfl_xor(wsum, off, 64);
        if (lane == 0) { wred[wid] = wm; wred[8 + wid] = wsum; }
        __syncthreads();
        float gm = fmaxf(fmaxf(wred[0], wred[1]), fmaxf(wred[2], wred[3]));
        float gs = wred[8]  * __expf(wred[0] - gm) + wred[9]  * __expf(wred[1] - gm)
                 + wred[10] * __expf(wred[2] - gm) + wred[11] * __expf(wred[3] - gm);
        float w = __expf(s - gm) / gs;
        wwts[tid] = w;
        __syncthreads();

        // fused update + read pass (quad mapping: 4 rows x 16 col-f4 per iter)
        {
            const int lm = lane & 15, q = lane >> 4;
            float4 k4 = ((const float4*)kv)[lm];
            float r0 = 0.f, r1 = 0.f, r2 = 0.f, r3 = 0.f;
#pragma unroll
            for (int i = 0; i < 16; ++i) {
                int n = wid * 64 + i * 4 + q;
                float wn = wwts[n];
                float4* mp = (float4*)(memA + n * MEMPAD + 4 * lm);
                float4 m4 = *mp;
                m4.x += wn * k4.x; m4.y += wn * k4.y; m4.z += wn * k4.z; m4.w += wn * k4.w;
                *mp = m4;
                r0 += wn * m4.x; r1 += wn * m4.y; r2 += wn * m4.z; r3 += wn * m4.w;
            }
            r0 += __shfl_xor(r0, 16, 64); r0 += __shfl_xor(r0, 32, 64);
            r1 += __shfl_xor(r1, 16, 64); r1 += __shfl_xor(r1, 32, 64);
            r2 += __shfl_xor(r2, 16, 64); r2 += __shfl_xor(r2, 32, 64);
            r3 += __shfl_xor(r3, 16, 64); r3 += __shfl_xor(r3, 32, 64);
            if (q == 0) {
                rp[wid * 64 + 4 * lm + 0] = r0;
                rp[wid * 64 + 4 * lm + 1] = r1;
                rp[wid * 64 + 4 * lm + 2] = r2;
                rp[wid * 64 + 4 * lm + 3] = r3;
            }
        }
        __syncthreads();
        if (tid < 64) {
            float rd = rp[tid] + rp[64 + tid] + rp[128 + tid] + rp[192 + tid];
            rstage[tid] = f2b(rd);
            RsF[(size_t)(t * BATCH + wg) * 64 + tid] = rd;   // epilogue-only
        }
        __syncthreads();
        if (tid < 8) {   // packed coherent r store: 8 x 16B
            uint4 rv = *(const uint4*)(rstage + tid * 8);
            stg_cv(hrg + wg * KHR + tid * 8, rv);
        }
        gridbar(bar, ++bar_phase);
    }
}

// ---------------- epilogue: ys = Hs@Wpre + Rs@Wro_eff + b_pre ; loss partials ----------------
__global__ void dnc_epilogue(char* __restrict__ ws, void* __restrict__ outv) {
    __shared__ float hs8[8][256];
    __shared__ float rs8[8][64];
    __shared__ float lacc;
    const float* HsF   = (const float*)(ws + WS_HS);
    const float* RsF   = (const float*)(ws + WS_RS);
    const float* WktF  = (const float*)(ws + WS_WKT);
    const float* WreF  = (const float*)(ws + WS_WROEFF);
    const float* WpreF = (const float*)(ws + WS_WPREF);
    const float* bpreF = (const float*)(ws + WS_BPREF);
    float* lossacc = (float*)(ws + WS_LOSS);
    const int bf = *(const int*)(ws + WS_FLAG);
    const int tid = threadIdx.x;
    const size_t r0 = (size_t)blockIdx.x * 8;
    if (tid == 0) lacc = 0.f;
    for (int i = tid; i < 8 * 256; i += 256) hs8[i >> 8][i & 255] = HsF[r0 * 256 + i];
    for (int i = tid; i < 8 * 64; i += 256)  rs8[i >> 6][i & 63]  = RsF[r0 * 64 + i];
    __syncthreads();
    // ys
    {
        const int rl = tid >> 5, c0 = (tid & 31) * 4;
        float a0 = bpreF[c0], a1 = bpreF[c0 + 1], a2 = bpreF[c0 + 2], a3 = bpreF[c0 + 3];
        for (int k = 0; k < 256; ++k) {
            float hv = hs8[rl][k];
            float4 w4 = *(const float4*)(WpreF + k * 128 + c0);
            a0 += hv * w4.x; a1 += hv * w4.y; a2 += hv * w4.z; a3 += hv * w4.w;
        }
        for (int m = 0; m < 64; ++m) {
            float rv = rs8[rl][m];
            float4 w4 = *(const float4*)(WreF + m * 128 + c0);
            a0 += rv * w4.x; a1 += rv * w4.y; a2 += rv * w4.z; a3 += rv * w4.w;
        }
        size_t o = (r0 + rl) * 128 + c0;
        if (bf) {
            u16* out = (u16*)outv;
            out[o] = f2b(a0); out[o + 1] = f2b(a1); out[o + 2] = f2b(a2); out[o + 3] = f2b(a3);
        } else {
            float* out = (float*)outv;
            out[o] = a0; out[o + 1] = a1; out[o + 2] = a2; out[o + 3] = a3;
        }
    }
    // loss: sum (h @ (Wkey - Wteach))^2
    {
        const int rl = tid >> 5, m0 = (tid & 31) * 2;
        float d0 = 0.f, d1 = 0.f;
        for (int k = 0; k < 256; ++k) {
            float hv = hs8[rl][k];
            d0 += hv * WktF[k * 64 + m0];
            d1 += hv * WktF[k * 64 + m0 + 1];
        }
        float p = d0 * d0 + d1 * d1;
#pragma unroll
        for (int off = 32; off > 0; off >>= 1) p += __shfl_xor(p, off, 64);
        if ((tid & 63) == 0) atomicAdd(&lacc, p);
        __syncthreads();
        if (tid == 0) atomicAdd(lossacc, lacc);
    }
}

__global__ void dnc_loss_fin(const char* __restrict__ ws, void* __restrict__ outv) {
    if (threadIdx.x == 0 && blockIdx.x == 0) {
        float l = *(const float*)(ws + WS_LOSS) * (1.f / 2048.f);
        if (*(const int*)(ws + WS_FLAG)) ((u16*)outv)[524288] = f2b(l);
        else                             ((float*)outv)[524288] = l;
    }
}

// ---------------- launch ----------------
extern "C" void kernel_launch(void* const* d_in, const int* in_sizes, int n_in,
                              void* d_out, int out_size, void* d_ws, size_t ws_size,
                              hipStream_t stream) {
    char* ws = (char*)d_ws;
    hipMemsetAsync(d_ws, 0, WS_ZSET, stream);   // barrier counter, loss acc, flag, hrg
    dnc_probe<<<1, 256, 0, stream>>>((const u16*)d_in[0], ws);
    dnc_normalize<<<512, 256, 0, stream>>>(d_in[0], d_in[1], d_in[2], d_in[3], d_in[4],
                                           d_in[5], d_in[6], d_in[7], d_in[8], d_in[9], ws);
    (void)hipFuncSetAttribute((const void*)dnc_prologue,
                              hipFuncAttributeMaxDynamicSharedMemorySize, 128 * 129 * 4);
    dnc_prologue<<<344, 256, 128 * 129 * 4, stream>>>(ws);
    (void)hipFuncSetAttribute((const void*)dnc_main,
                              hipFuncAttributeMaxDynamicSharedMemorySize, LDS_TOTAL);
    dnc_main<<<32, 256, LDS_TOTAL, stream>>>(ws);
    dnc_epilogue<<<512, 256, 0, stream>>>(ws, d_out);
    dnc_loss_fin<<<1, 64, 0, stream>>>(ws, d_out);
}

// Round 6
// 1163.205 us; speedup vs baseline: 1.4106x; 1.0687x over previous
//
#include <hip/hip_runtime.h>

// ---------------- types / helpers ----------------
typedef unsigned short u16;
typedef unsigned long long u64;
typedef short short8 __attribute__((ext_vector_type(8)));
typedef float f32x4 __attribute__((ext_vector_type(4)));

__device__ __forceinline__ float b2f(u16 u) {
    unsigned x = ((unsigned)u) << 16;
    return __builtin_bit_cast(float, x);
}
__device__ __forceinline__ u16 f2b(float f) {
    unsigned u = __builtin_bit_cast(unsigned, f);
    u += 0x7FFFu + ((u >> 16) & 1u);   // RNE
    return (u16)(u >> 16);
}
__device__ __forceinline__ float sigm(float x) { return 1.f / (1.f + __expf(-x)); }
__device__ __forceinline__ float tanh_(float x) { return 1.f - 2.f / (__expf(2.f * x) + 1.f); }

// ---- coherent (L1+L2-bypass) accesses ----
__device__ __forceinline__ uint4 ldg_cv(const void* p) {
    uint4 v;
    asm volatile("global_load_dwordx4 %0, %1, off sc0 sc1\n\ts_waitcnt vmcnt(0)"
                 : "=v"(v) : "v"(p) : "memory");
    return v;
}
// issue-only: no waitcnt — pair with wait_vm0() after independent work
__device__ __forceinline__ void ldg_cv4_issue(const void* p0, const void* p1, const void* p2,
                                              const void* p3, uint4& a, uint4& b, uint4& c, uint4& d) {
    asm volatile(
        "global_load_dwordx4 %0, %4, off sc0 sc1\n\t"
        "global_load_dwordx4 %1, %5, off sc0 sc1\n\t"
        "global_load_dwordx4 %2, %6, off sc0 sc1\n\t"
        "global_load_dwordx4 %3, %7, off sc0 sc1"
        : "=v"(a), "=v"(b), "=v"(c), "=v"(d)
        : "v"(p0), "v"(p1), "v"(p2), "v"(p3) : "memory");
}
__device__ __forceinline__ void wait_vm0() {
    asm volatile("s_waitcnt vmcnt(0)" ::: "memory");
}
// stores: two relaxed agent-scope u64 atomic stores (16B)
__device__ __forceinline__ void stg_cv(void* p, uint4 v) {
    u64 lo = ((u64)v.y << 32) | (u64)v.x;
    u64 hi = ((u64)v.w << 32) | (u64)v.z;
    __hip_atomic_store((u64*)p,     lo, __ATOMIC_RELAXED, __HIP_MEMORY_SCOPE_AGENT);
    __hip_atomic_store((u64*)p + 1, hi, __ATOMIC_RELAXED, __HIP_MEMORY_SCOPE_AGENT);
}

// ---------------- problem constants ----------------
#define T_STEPS 128
#define BATCH   32
#define KHR     320      // 64 (read) + 256 (h)
#define PADK    328      // hr_lds row pad (bf16 elems)
#define MEMPAD  68       // mem row stride in floats
#define WKPAD   264      // wkeyT row pad (bf16 elems)

// ---------------- workspace layout (bytes) ----------------
#define WS_BAR      0                         // u32 [32] barrier flags = 128
#define WS_LOSS     128
#define WS_FLAG     160
#define WS_HRG      192                       // u16 [32][320] = 20480 (ends 20672)
#define WS_ZSET     41088                     // memset range end
// normalized fp32 inputs
#define WS_XSF      41216                     // 524288 f32
#define WS_MEM0F    2138368                   // 524288 f32
#define WS_WLF      4235520                   // 655360 f32
#define WS_BLF      6856960                   // 1024 f32
#define WS_WPREF    6861056                   // 32768 f32
#define WS_BPREF    6992128                   // 128 f32
#define WS_WKEYF    6992640                   // 16384 f32
#define WS_WBETAF   7058176                   // 256 f32
#define WS_WTEACHF  7059200                   // 16384 f32
#define WS_WROF     7124736                   // 32768 f32
// derived
#define WS_XW       7255808                   // f32 [4096][1024] = 16777216
#define WS_WREFF    24033024                  // f32 [64][1024]   = 262144
#define WS_WKT      24295168                  // f32 [256][64]    = 65536
#define WS_WROEFF   24360704                  // f32 [64][128]    = 32768
#define WS_HS       24393472                  // f32 [4096][256]  = 4194304
#define WS_RS       28587776                  // f32 [4096][64]   = 1048576

// ---------------- LDS layout (bytes) ----------------
#define HR_OFF   0         // u16 [32][328]            20992
#define WF_OFF   20992     // u16 [10][4][32][8]       20480
#define WK_OFF   41472     // u16 [64][264]            33792
#define MEM_OFF  75264     // f32 [256][68]            69632
#define Z_OFF    144896    // f32 [32][36]             4608
#define C_OFF    149504    // f32 [32][8]              1024
#define KV_OFF   151552    // f32 [64]                 256
#define WW_OFF   151808    // f32 [256]                1024
#define KP_OFF   152832    // f32 [4][64]              1024
#define RP_OFF   153856    // f32 [4][64]              1024
#define BR_OFF   154880    // f32 [16]
#define WR_OFF   154944    // f32 [16]
#define SC_OFF   155008    // f32 scalars
#define WB_OFF   155072    // f32 [256]                1024
#define HST_OFF  156096    // u16 [256]                512
#define RST_OFF  156608    // u16 [64]                 128
#define LDS_TOTAL 156736

// ---------------- flag-array grid barrier (32 resident wgs) ----------------
// arrival: 1 relaxed agent store to flags[wg]; detect: 32 lanes read all flags + ballot.
// __syncthreads drains vmcnt (incl. stores) per wave before s_barrier, so all
// coherent data stores are at the LLC before the flag store issues.
__device__ __forceinline__ void gridbar(unsigned* flags, unsigned phase) {
    __syncthreads();
    if (threadIdx.x < 64) {
        if (threadIdx.x == 0)
            __hip_atomic_store(flags + blockIdx.x, phase, __ATOMIC_RELAXED,
                               __HIP_MEMORY_SCOPE_AGENT);
        long guard = 0;
        for (;;) {
            unsigned v = __hip_atomic_load(flags + (threadIdx.x & 31), __ATOMIC_RELAXED,
                                           __HIP_MEMORY_SCOPE_AGENT);
            if (__ballot(v < phase) == 0ull) break;
            if (++guard > 2000000L) break;   // bail instead of hanging
            __builtin_amdgcn_s_sleep(1);
        }
    }
    __syncthreads();
}

// ---------------- dtype probe: f32 vs bf16 ----------------
__global__ void dnc_probe(const u16* __restrict__ xs_u16, char* __restrict__ ws) {
    __shared__ int cnt;
    if (threadIdx.x == 0) cnt = 0;
    __syncthreads();
    int c = 0;
    for (int i = threadIdx.x; i < 1024; i += 256) {
        int e = (xs_u16[i] >> 7) & 0xFF;
        if (e >= 96 && e <= 135) c++;
    }
    atomicAdd(&cnt, c);
    __syncthreads();
    if (threadIdx.x == 0) *(int*)(ws + WS_FLAG) = (cnt > 820) ? 1 : 0;   // 1 = bf16
}

// ---------------- normalize all inputs to fp32 in ws ----------------
__global__ void dnc_normalize(const void* s0, const void* s1, const void* s2, const void* s3,
                              const void* s4, const void* s5, const void* s6, const void* s7,
                              const void* s8, const void* s9, char* __restrict__ ws) {
    const void* srcs[10] = {s0, s1, s2, s3, s4, s5, s6, s7, s8, s9};
    const int sizes[10] = {524288, 524288, 655360, 1024, 32768, 128, 16384, 256, 16384, 32768};
    const int bases[10] = {WS_XSF, WS_MEM0F, WS_WLF, WS_BLF, WS_WPREF, WS_BPREF,
                           WS_WKEYF, WS_WBETAF, WS_WTEACHF, WS_WROF};
    const int bf = *(const int*)(ws + WS_FLAG);
    const int gt = blockIdx.x * 256 + threadIdx.x, gs = gridDim.x * 256;
    for (int s = 0; s < 10; ++s) {
        float* dst = (float*)(ws + bases[s]);
        const int n = sizes[s];
        if (bf) {
            const u16* p = (const u16*)srcs[s];
            for (int i = gt; i < n; i += gs) dst[i] = b2f(p[i]);
        } else {
            const float* p = (const float*)srcs[s];
            for (int i = gt; i < n; i += gs) dst[i] = p[i];
        }
    }
}

// ---------------- prologue: xW 2D-blocked GEMM + weight folds (fp32) ----------------
__global__ void dnc_prologue(char* __restrict__ ws) {
    extern __shared__ float xls[];   // [128][129]
    const float* XSF     = (const float*)(ws + WS_XSF);
    const float* WLF     = (const float*)(ws + WS_WLF);
    const float* BLF     = (const float*)(ws + WS_BLF);
    const float* WKEYF   = (const float*)(ws + WS_WKEYF);
    const float* WTEACHF = (const float*)(ws + WS_WTEACHF);
    const float* WROF    = (const float*)(ws + WS_WROF);
    float* xW  = (float*)(ws + WS_XW);
    float* WrE = (float*)(ws + WS_WREFF);
    float* Wkt = (float*)(ws + WS_WKT);
    float* Wre = (float*)(ws + WS_WROEFF);
    const int wg = blockIdx.x, tid = threadIdx.x;
    if (wg < 256) {
        const int rb = wg >> 3, cb = wg & 7;
        const float4* xsrc = (const float4*)(XSF + (size_t)rb * 16384);
        for (int i = tid; i < 4096; i += 256) {
            float4 v = xsrc[i];
            int row = i >> 5, c4 = (i & 31) * 4;
            float* d = xls + row * 129 + c4;
            d[0] = v.x; d[1] = v.y; d[2] = v.z; d[3] = v.w;
        }
        __syncthreads();
        const int tr = tid >> 4, tc = tid & 15;
        const int c0 = cb * 128 + tc * 8;
        float acc[8][8];
#pragma unroll
        for (int rr = 0; rr < 8; ++rr)
#pragma unroll
            for (int cc = 0; cc < 8; ++cc) acc[rr][cc] = BLF[c0 + cc];
        for (int k = 0; k < 128; ++k) {
            float4 wA = *(const float4*)(WLF + (size_t)k * 1024 + c0);
            float4 wB = *(const float4*)(WLF + (size_t)k * 1024 + c0 + 4);
            float w[8] = {wA.x, wA.y, wA.z, wA.w, wB.x, wB.y, wB.z, wB.w};
#pragma unroll
            for (int rr = 0; rr < 8; ++rr) {
                float xv = xls[(tr * 8 + rr) * 129 + k];
#pragma unroll
                for (int cc = 0; cc < 8; ++cc) acc[rr][cc] += xv * w[cc];
            }
        }
#pragma unroll
        for (int rr = 0; rr < 8; ++rr) {
            size_t o = (size_t)(rb * 128 + tr * 8 + rr) * 1024 + c0;
            *(float4*)(xW + o)     = make_float4(acc[rr][0], acc[rr][1], acc[rr][2], acc[rr][3]);
            *(float4*)(xW + o + 4) = make_float4(acc[rr][4], acc[rr][5], acc[rr][6], acc[rr][7]);
        }
    } else if (wg < 320) {
        const int m = wg - 256;
        const int c = tid * 4;
#pragma unroll
        for (int e = 0; e < 4; ++e) {
            float s = 0.f;
#pragma unroll
            for (int rr = 0; rr < 4; ++rr) s += WLF[(size_t)(128 + 4 * m + rr) * 1024 + c + e];
            WrE[m * 1024 + c + e] = s;
        }
    } else if (wg < 336) {
        const int i = (wg - 320) * 1024 + tid * 4;
#pragma unroll
        for (int e = 0; e < 4; ++e) Wkt[i + e] = WKEYF[i + e] - WTEACHF[i + e];
    } else if (wg < 344) {
        const int i = (wg - 336) * 1024 + tid * 4;
#pragma unroll
        for (int e = 0; e < 4; ++e) {
            int m = (i + e) >> 7, c = (i + e) & 127;
            float s = 0.f;
#pragma unroll
            for (int rr = 0; rr < 4; ++rr) s += WROF[(4 * m + rr) * 128 + c];
            Wre[i + e] = s;
        }
    }
}

// ---------------- main persistent kernel: 32 wgs, 2 grid barriers / step ----------------
// K-split: z = xW + r@Wr (K=64, phase A) + h@Wh (K=256, phase B, register-carried).
__global__ __launch_bounds__(256, 1) void dnc_main(char* __restrict__ ws) {
    extern __shared__ char smem[];
    u16*   hr_lds = (u16*)(smem + HR_OFF);
    u16*   wfrag  = (u16*)(smem + WF_OFF);
    u16*   wkeyT  = (u16*)(smem + WK_OFF);
    float* memA   = (float*)(smem + MEM_OFF);
    float* z_lds  = (float*)(smem + Z_OFF);
    float* c_lds  = (float*)(smem + C_OFF);
    float* kv     = (float*)(smem + KV_OFF);
    float* wwts   = (float*)(smem + WW_OFF);
    float* kpart  = (float*)(smem + KP_OFF);
    float* rp     = (float*)(smem + RP_OFF);
    float* bred   = (float*)(smem + BR_OFF);
    float* wred   = (float*)(smem + WR_OFF);
    float* sc     = (float*)(smem + SC_OFF);
    float* wbF    = (float*)(smem + WB_OFF);
    u16*   hstage = (u16*)(smem + HST_OFF);
    u16*   rstage = (u16*)(smem + RST_OFF);

    const int tid  = threadIdx.x;
    const int wg   = blockIdx.x;     // col-slice id AND batch id (0..31)
    const int lane = tid & 63;
    const int wid  = tid >> 6;       // wave 0..3

    unsigned* flags = (unsigned*)(ws + WS_BAR);
    u16* hrg        = (u16*)(ws + WS_HRG);             // [32][320] bf16
    const float* xWF     = (const float*)(ws + WS_XW);
    const float* WrEffF  = (const float*)(ws + WS_WREFF);
    const float* WLF     = (const float*)(ws + WS_WLF);
    const float* WKEYF   = (const float*)(ws + WS_WKEYF);
    const float* WBETAF  = (const float*)(ws + WS_WBETAF);
    const float* MEM0F   = (const float*)(ws + WS_MEM0F);
    float* HsF = (float*)(ws + WS_HS);
    float* RsF = (float*)(ws + WS_RS);

    // ---- one-time LDS init ----
    for (int i = tid; i < 32 * PADK; i += 256) hr_lds[i] = 0;   // h(-1)=0, r(-1)=0
    for (int idx = tid; idx < 10240; idx += 256) {
        int k = idx >> 5, c = idx & 31;
        int kt = k >> 5, q = (k >> 3) & 3, j = k & 7;
        int gcol = (c >> 3) * 256 + wg * 8 + (c & 7);
        float v = (k < 64) ? WrEffF[k * 1024 + gcol]
                           : WLF[(size_t)(384 + (k - 64)) * 1024 + gcol];
        wfrag[((kt * 4 + q) * 32 + c) * 8 + j] = f2b(v);
    }
    for (int i = tid; i < 256 * 64; i += 256) {   // wkeyT[m][k] = Wkey[k][m] (bf16)
        int k = i >> 6, m = i & 63;
        wkeyT[m * WKPAD + k] = f2b(WKEYF[i]);
    }
    wbF[tid]   = WBETAF[tid];
    c_lds[tid] = 0.f;
    for (int i = tid; i < 256 * 64; i += 256) {   // mem state fp32
        int n = i >> 6, m = i & 63;
        memA[n * MEMPAD + m] = MEM0F[wg * 16384 + i];
    }
    __syncthreads();

    const int bt = wid & 1, ct = wid >> 1;   // MFMA tile assignment
    const int fm = lane & 15, fq = lane >> 4;
    const int pb = tid >> 3, pu = tid & 7;   // batch / unit for pointwise & staging
    unsigned bar_phase = 0;

    // xW gates for t=0; h@Wh accumulator for t=0 is 0 (h(-1)=0)
    float xg0, xg1, xg2, xg3;
    {
        const size_t xb = (size_t)pb * 1024 + wg * 8 + pu;
        xg0 = xWF[xb]; xg1 = xWF[xb + 256]; xg2 = xWF[xb + 512]; xg3 = xWF[xb + 768];
    }
    f32x4 hWacc = {0.f, 0.f, 0.f, 0.f};

    for (int t = 0; t < T_STEPS; ++t) {
        // ================= phase A =================
        // stage r(t-1) (8 KB total) into hr_lds r-region
        {
            uint4 rv = ldg_cv(hrg + pb * KHR + pu * 8);
            *(uint4*)(hr_lds + pb * PADK + pu * 8) = rv;
        }
        __syncthreads();

        // rW MFMA (kt=0,1) accumulating onto carried h@Wh
        f32x4 acc = hWacc;
#pragma unroll
        for (int kt = 0; kt < 2; ++kt) {
            short8 a = *(const short8*)(hr_lds + (bt * 16 + fm) * PADK + kt * 32 + fq * 8);
            short8 b = *(const short8*)(wfrag + ((kt * 4 + fq) * 32 + ct * 16 + fm) * 8);
            acc = __builtin_amdgcn_mfma_f32_16x16x32_bf16(a, b, acc, 0, 0, 0);
        }
#pragma unroll
        for (int r = 0; r < 4; ++r) {
            int bb = bt * 16 + fq * 4 + r;        // C/D: row = quad*4+reg
            int cc = ct * 16 + fm;                //       col = lane&15
            z_lds[bb * 36 + cc] = acc[r];
        }
        __syncthreads();

        // LSTM pointwise for hidden units [8*wg, 8*wg+8), all batches
        {
            float iv = z_lds[pb * 36 + pu]      + xg0;
            float fv = z_lds[pb * 36 + 8 + pu]  + xg1;
            float gv = z_lds[pb * 36 + 16 + pu] + xg2;
            float ov = z_lds[pb * 36 + 24 + pu] + xg3;
            float co = c_lds[pb * 8 + pu];
            float cn = sigm(fv) * co + sigm(iv) * tanh_(gv);
            float hn = sigm(ov) * tanh_(cn);
            c_lds[pb * 8 + pu] = cn;
            hstage[pb * 8 + pu] = f2b(hn);
            HsF[(size_t)(t * BATCH + pb) * 256 + wg * 8 + pu] = hn;   // epilogue-only
        }
        __syncthreads();
        if (tid < 32) {   // packed coherent h store: 16B per batch row
            uint4 hv = *(const uint4*)(hstage + tid * 8);
            stg_cv(hrg + tid * KHR + 64 + wg * 8, hv);
        }
        gridbar(flags, ++bar_phase);

        // ================= phase B =================
        // issue h(t) prefetch (16 KB total), no waitcnt yet
        uint4 ha, hb4, hc, hd;
        {
            const u16* src = hrg + pb * KHR + 64 + pu * 32;
            ldg_cv4_issue(src, src + 8, src + 16, src + 24, ha, hb4, hc, hd);
        }
        // xW gates for t+1 (plain cached loads, drain at wait_vm0)
        {
            int tn = (t + 1 < T_STEPS) ? t + 1 : 127;
            const size_t xb = (size_t)(tn * BATCH + pb) * 1024 + wg * 8 + pu;
            xg0 = xWF[xb]; xg1 = xWF[xb + 256]; xg2 = xWF[xb + 512]; xg3 = xWF[xb + 768];
        }
        // h-independent work while loads fly: ||mem_n||^2 (mem final since last update)
        float nr2 = 0.f;
        {
            const float4* mrow = (const float4*)(memA + tid * MEMPAD);
#pragma unroll
            for (int i = 0; i < 16; ++i) {
                float4 m4 = mrow[i];
                nr2 += m4.x * m4.x + m4.y * m4.y + m4.z * m4.z + m4.w * m4.w;
            }
        }
        wait_vm0();
        {
            u16* dst = hr_lds + pb * PADK + 64 + pu * 32;
            *(uint4*)(dst)      = ha;
            *(uint4*)(dst + 8)  = hb4;
            *(uint4*)(dst + 16) = hc;
            *(uint4*)(dst + 24) = hd;
        }
        __syncthreads();

        // hW MFMA (kt=2..9) -> fresh accumulator carried to phase A of t+1
        {
            f32x4 hz = {0.f, 0.f, 0.f, 0.f};
#pragma unroll
            for (int kt = 2; kt < 10; ++kt) {
                short8 a = *(const short8*)(hr_lds + (bt * 16 + fm) * PADK + kt * 32 + fq * 8);
                short8 b = *(const short8*)(wfrag + ((kt * 4 + fq) * 32 + ct * 16 + fm) * 8);
                hz = __builtin_amdgcn_mfma_f32_16x16x32_bf16(a, b, hz, 0, 0, 0);
            }
            hWacc = hz;
        }

        // M phase: this wg owns batch b = wg; h_b in hr_lds[wg]
        const u16* hrow = hr_lds + wg * PADK + 64;
        {
            float a = 0.f;
#pragma unroll
            for (int i = 0; i < 8; ++i) {
                short8 w8 = *(const short8*)(wkeyT + lane * WKPAD + wid * 64 + i * 8);
                short8 h8 = *(const short8*)(hrow + wid * 64 + i * 8);
#pragma unroll
                for (int e = 0; e < 8; ++e)
                    a += b2f((u16)h8[e]) * b2f((u16)w8[e]);
            }
            kpart[wid * 64 + lane] = a;
        }
        {
            float bp = b2f(hrow[tid]) * wbF[tid];
#pragma unroll
            for (int off = 32; off > 0; off >>= 1) bp += __shfl_xor(bp, off, 64);
            if (lane == 0) bred[wid] = bp;
        }
        __syncthreads();
        if (tid < 64) {   // finalize k, ||k||
            float kk = kpart[tid] + kpart[64 + tid] + kpart[128 + tid] + kpart[192 + tid];
            kv[tid] = kk;
            float k2 = kk * kk;
#pragma unroll
            for (int off = 32; off > 0; off >>= 1) k2 += __shfl_xor(k2, off, 64);
            if (tid == 0) sc[1] = sqrtf(k2);
        } else if (tid == 64) {   // beta = softplus
            float zb = bred[0] + bred[1] + bred[2] + bred[3];
            sc[0] = logf(1.f + __expf(zb));
        }
        __syncthreads();
        const float beta = sc[0], knorm = sc[1];

        // num pass (nr2 precomputed above): thread = mem row
        float num = 0.f;
        {
            const float4* mrow = (const float4*)(memA + tid * MEMPAD);
            const float4* k4p  = (const float4*)kv;
#pragma unroll
            for (int i = 0; i < 16; ++i) {
                float4 m4 = mrow[i], k4 = k4p[i];
                num += m4.x * k4.x + m4.y * k4.y + m4.z * k4.z + m4.w * k4.w;
            }
        }
        float den = fmaxf(sqrtf(nr2) * knorm, 1e-8f);
        float s   = beta * (num / den);
        // single-pass per-wave max+sumexp, then combine
        float wm = s;
#pragma unroll
        for (int off = 32; off > 0; off >>= 1) wm = fmaxf(wm, __shfl_xor(wm, off, 64));
        float ev = __expf(s - wm);
        float wsum = ev;
#pragma unroll
        for (int off = 32; off > 0; off >>= 1) wsum += __shfl_xor(wsum, off, 64);
        if (lane == 0) { wred[wid] = wm; wred[8 + wid] = wsum; }
        __syncthreads();
        float gm = fmaxf(fmaxf(wred[0], wred[1]), fmaxf(wred[2], wred[3]));
        float gsum = wred[8]  * __expf(wred[0] - gm) + wred[9]  * __expf(wred[1] - gm)
                   + wred[10] * __expf(wred[2] - gm) + wred[11] * __expf(wred[3] - gm);
        float w = __expf(s - gm) / gsum;
        wwts[tid] = w;
        __syncthreads();

        // fused update + read pass (quad mapping: 4 rows x 16 col-f4 per iter)
        {
            const int lm = lane & 15, q = lane >> 4;
            float4 k4 = ((const float4*)kv)[lm];
            float r0 = 0.f, r1 = 0.f, r2 = 0.f, r3 = 0.f;
#pragma unroll
            for (int i = 0; i < 16; ++i) {
                int n = wid * 64 + i * 4 + q;
                float wn = wwts[n];
                float4* mp = (float4*)(memA + n * MEMPAD + 4 * lm);
                float4 m4 = *mp;
                m4.x += wn * k4.x; m4.y += wn * k4.y; m4.z += wn * k4.z; m4.w += wn * k4.w;
                *mp = m4;
                r0 += wn * m4.x; r1 += wn * m4.y; r2 += wn * m4.z; r3 += wn * m4.w;
            }
            r0 += __shfl_xor(r0, 16, 64); r0 += __shfl_xor(r0, 32, 64);
            r1 += __shfl_xor(r1, 16, 64); r1 += __shfl_xor(r1, 32, 64);
            r2 += __shfl_xor(r2, 16, 64); r2 += __shfl_xor(r2, 32, 64);
            r3 += __shfl_xor(r3, 16, 64); r3 += __shfl_xor(r3, 32, 64);
            if (q == 0) {
                rp[wid * 64 + 4 * lm + 0] = r0;
                rp[wid * 64 + 4 * lm + 1] = r1;
                rp[wid * 64 + 4 * lm + 2] = r2;
                rp[wid * 64 + 4 * lm + 3] = r3;
            }
        }
        __syncthreads();
        if (tid < 64) {
            float rd = rp[tid] + rp[64 + tid] + rp[128 + tid] + rp[192 + tid];
            rstage[tid] = f2b(rd);
            RsF[(size_t)(t * BATCH + wg) * 64 + tid] = rd;   // epilogue-only
        }
        __syncthreads();
        if (tid < 8) {   // packed coherent r store: 8 x 16B
            uint4 rv = *(const uint4*)(rstage + tid * 8);
            stg_cv(hrg + wg * KHR + tid * 8, rv);
        }
        gridbar(flags, ++bar_phase);
    }
}

// ---------------- epilogue: ys = Hs@Wpre + Rs@Wro_eff + b_pre ; loss partials ----------------
__global__ void dnc_epilogue(char* __restrict__ ws, void* __restrict__ outv) {
    __shared__ float hs8[8][256];
    __shared__ float rs8[8][64];
    __shared__ float lacc;
    const float* HsF   = (const float*)(ws + WS_HS);
    const float* RsF   = (const float*)(ws + WS_RS);
    const float* WktF  = (const float*)(ws + WS_WKT);
    const float* WreF  = (const float*)(ws + WS_WROEFF);
    const float* WpreF = (const float*)(ws + WS_WPREF);
    const float* bpreF = (const float*)(ws + WS_BPREF);
    float* lossacc = (float*)(ws + WS_LOSS);
    const int bf = *(const int*)(ws + WS_FLAG);
    const int tid = threadIdx.x;
    const size_t r0 = (size_t)blockIdx.x * 8;
    if (tid == 0) lacc = 0.f;
    for (int i = tid; i < 8 * 256; i += 256) hs8[i >> 8][i & 255] = HsF[r0 * 256 + i];
    for (int i = tid; i < 8 * 64; i += 256)  rs8[i >> 6][i & 63]  = RsF[r0 * 64 + i];
    __syncthreads();
    // ys
    {
        const int rl = tid >> 5, c0 = (tid & 31) * 4;
        float a0 = bpreF[c0], a1 = bpreF[c0 + 1], a2 = bpreF[c0 + 2], a3 = bpreF[c0 + 3];
        for (int k = 0; k < 256; ++k) {
            float hv = hs8[rl][k];
            float4 w4 = *(const float4*)(WpreF + k * 128 + c0);
            a0 += hv * w4.x; a1 += hv * w4.y; a2 += hv * w4.z; a3 += hv * w4.w;
        }
        for (int m = 0; m < 64; ++m) {
            float rv = rs8[rl][m];
            float4 w4 = *(const float4*)(WreF + m * 128 + c0);
            a0 += rv * w4.x; a1 += rv * w4.y; a2 += rv * w4.z; a3 += rv * w4.w;
        }
        size_t o = (r0 + rl) * 128 + c0;
        if (bf) {
            u16* out = (u16*)outv;
            out[o] = f2b(a0); out[o + 1] = f2b(a1); out[o + 2] = f2b(a2); out[o + 3] = f2b(a3);
        } else {
            float* out = (float*)outv;
            out[o] = a0; out[o + 1] = a1; out[o + 2] = a2; out[o + 3] = a3;
        }
    }
    // loss: sum (h @ (Wkey - Wteach))^2
    {
        const int rl = tid >> 5, m0 = (tid & 31) * 2;
        float d0 = 0.f, d1 = 0.f;
        for (int k = 0; k < 256; ++k) {
            float hv = hs8[rl][k];
            d0 += hv * WktF[k * 64 + m0];
            d1 += hv * WktF[k * 64 + m0 + 1];
        }
        float p = d0 * d0 + d1 * d1;
#pragma unroll
        for (int off = 32; off > 0; off >>= 1) p += __shfl_xor(p, off, 64);
        if ((tid & 63) == 0) atomicAdd(&lacc, p);
        __syncthreads();
        if (tid == 0) atomicAdd(lossacc, lacc);
    }
}

__global__ void dnc_loss_fin(const char* __restrict__ ws, void* __restrict__ outv) {
    if (threadIdx.x == 0 && blockIdx.x == 0) {
        float l = *(const float*)(ws + WS_LOSS) * (1.f / 2048.f);
        if (*(const int*)(ws + WS_FLAG)) ((u16*)outv)[524288] = f2b(l);
        else                             ((float*)outv)[524288] = l;
    }
}

// ---------------- launch ----------------
extern "C" void kernel_launch(void* const* d_in, const int* in_sizes, int n_in,
                              void* d_out, int out_size, void* d_ws, size_t ws_size,
                              hipStream_t stream) {
    char* ws = (char*)d_ws;
    hipMemsetAsync(d_ws, 0, WS_ZSET, stream);   // barrier flags, loss acc, dtype flag, hrg
    dnc_probe<<<1, 256, 0, stream>>>((const u16*)d_in[0], ws);
    dnc_normalize<<<512, 256, 0, stream>>>(d_in[0], d_in[1], d_in[2], d_in[3], d_in[4],
                                           d_in[5], d_in[6], d_in[7], d_in[8], d_in[9], ws);
    (void)hipFuncSetAttribute((const void*)dnc_prologue,
                              hipFuncAttributeMaxDynamicSharedMemorySize, 128 * 129 * 4);
    dnc_prologue<<<344, 256, 128 * 129 * 4, stream>>>(ws);
    (void)hipFuncSetAttribute((const void*)dnc_main,
                              hipFuncAttributeMaxDynamicSharedMemorySize, LDS_TOTAL);
    dnc_main<<<32, 256, LDS_TOTAL, stream>>>(ws);
    dnc_epilogue<<<512, 256, 0, stream>>>(ws, d_out);
    dnc_loss_fin<<<1, 64, 0, stream>>>(ws, d_out);
}